// Round 1
// baseline (804.161 us; speedup 1.0000x reference)
//
#include <hip/hip_runtime.h>

// ChebConv x2: N=100000 nodes, E=1600000 edges, K=3, IN=128, HID=64, OUT=40
// Strategy:
//   1) build dst-CSR (count -> scan -> scatter) + dinv from src-degree
//   2) prop via wave-per-node CSR gather (no atomics in hot loops)
//   3) fused 3-source GEMM with effective weights [W0 - W2, W1, 2*W2]
//      (folds the Chebyshev recurrence Tx2 = 2*prop(Tx1) - Tx0)

__global__ void k_count(const int* __restrict__ src, const int* __restrict__ dst, int E,
                        int* __restrict__ deg, int* __restrict__ indeg) {
  int e = blockIdx.x * blockDim.x + threadIdx.x;
  if (e < E) {
    atomicAdd(&deg[src[e]], 1);
    atomicAdd(&indeg[dst[e]], 1);
  }
}

__global__ void k_dinv(const int* __restrict__ deg, float* __restrict__ dinv, int n) {
  int i = blockIdx.x * blockDim.x + threadIdx.x;
  if (i < n) {
    int d = deg[i];
    dinv[i] = (d > 0) ? rsqrtf((float)d) : 0.f;
  }
}

// exclusive scan phase 1: 1024 elements per block (256 threads x 4)
__global__ void k_scan1(const int* __restrict__ in, int n, int* __restrict__ out,
                        int* __restrict__ bsum) {
  __shared__ int sh[256];
  const int t = threadIdx.x;
  const int base = blockIdx.x * 1024;
  int v[4];
  int s = 0;
#pragma unroll
  for (int i = 0; i < 4; i++) {
    int idx = base + t * 4 + i;
    v[i] = (idx < n) ? in[idx] : 0;
    s += v[i];
  }
  int run = s;
  sh[t] = run;
  __syncthreads();
  for (int off = 1; off < 256; off <<= 1) {
    int x = (t >= off) ? sh[t - off] : 0;
    __syncthreads();
    run += x;
    sh[t] = run;
    __syncthreads();
  }
  if (t == 255) bsum[blockIdx.x] = run;
  int p = run - s;  // exclusive prefix for this thread
#pragma unroll
  for (int i = 0; i < 4; i++) {
    int idx = base + t * 4 + i;
    if (idx < n) out[idx] = p;
    p += v[i];
  }
}

// exclusive scan of block sums (nb <= 256), in place
__global__ void k_scan2(int* __restrict__ bsum, int nb) {
  __shared__ int sh[256];
  const int t = threadIdx.x;
  int v = (t < nb) ? bsum[t] : 0;
  int run = v;
  sh[t] = run;
  __syncthreads();
  for (int off = 1; off < 256; off <<= 1) {
    int x = (t >= off) ? sh[t - off] : 0;
    __syncthreads();
    run += x;
    sh[t] = run;
    __syncthreads();
  }
  if (t < nb) bsum[t] = run - v;
}

__global__ void k_scan3(int* __restrict__ row_ptr, int n, const int* __restrict__ bsum,
                        int* __restrict__ pos, int Etot) {
  int i = blockIdx.x * blockDim.x + threadIdx.x;
  if (i < n) {
    int v = row_ptr[i] + bsum[i >> 10];
    row_ptr[i] = v;
    pos[i] = v;
  }
  if (i == n) row_ptr[n] = Etot;
}

__global__ void k_scatter(const int* __restrict__ src, const int* __restrict__ dst, int E,
                          const float* __restrict__ dinv, int* __restrict__ pos,
                          int* __restrict__ csr_src, float* __restrict__ csr_norm) {
  int e = blockIdx.x * blockDim.x + threadIdx.x;
  if (e >= E) return;
  int s = src[e], d = dst[e];
  float nm = -dinv[s] * dinv[d];
  int idx = atomicAdd(&pos[d], 1);
  csr_src[idx] = s;
  csr_norm[idx] = nm;
}

// effective weights: Weff[0] = W[0]-W[2], Weff[1] = W[1], Weff[2] = 2*W[2], cols padded to 64
__global__ void k_weff(const float* __restrict__ W, const float* __restrict__ b,
                       float* __restrict__ Weff, float* __restrict__ beff, int INF, int OUTC) {
  int i = blockIdx.x * blockDim.x + threadIdx.x;
  if (i < 64) beff[i] = (i < OUTC) ? b[i] : 0.f;
  int total = 3 * INF * 64;
  if (i >= total) return;
  int col = i & 63;
  int kk = (i >> 6) % INF;
  int m = i / (INF * 64);
  float v = 0.f;
  if (col < OUTC) {
    if (m == 0)      v = W[(0 * INF + kk) * OUTC + col] - W[(2 * INF + kk) * OUTC + col];
    else if (m == 1) v = W[(1 * INF + kk) * OUTC + col];
    else             v = 2.f * W[(2 * INF + kk) * OUTC + col];
  }
  Weff[i] = v;
}

// wave-per-node CSR propagation: out[node] = sum_j norm[j] * h[csr_src[j]]
template <int F>
__global__ __launch_bounds__(256) void k_prop(const float* __restrict__ h,
                                              const int* __restrict__ csr_src,
                                              const float* __restrict__ csr_norm,
                                              const int* __restrict__ row_ptr,
                                              float* __restrict__ out, int n) {
  const int lane = threadIdx.x & 63;
  const int node = (blockIdx.x * blockDim.x + threadIdx.x) >> 6;
  if (node >= n) return;
  const int beg = row_ptr[node];
  const int end = row_ptr[node + 1];
  if (F == 128) {
    float ax = 0.f, ay = 0.f;
    int j = beg;
    for (; j + 1 < end; j += 2) {
      int s0 = csr_src[j], s1 = csr_src[j + 1];
      float w0 = csr_norm[j], w1 = csr_norm[j + 1];
      float2 p0 = *reinterpret_cast<const float2*>(h + (size_t)s0 * 128 + lane * 2);
      float2 p1 = *reinterpret_cast<const float2*>(h + (size_t)s1 * 128 + lane * 2);
      ax += w0 * p0.x + w1 * p1.x;
      ay += w0 * p0.y + w1 * p1.y;
    }
    if (j < end) {
      int s0 = csr_src[j];
      float w0 = csr_norm[j];
      float2 p0 = *reinterpret_cast<const float2*>(h + (size_t)s0 * 128 + lane * 2);
      ax += w0 * p0.x;
      ay += w0 * p0.y;
    }
    float2 r;
    r.x = ax;
    r.y = ay;
    *reinterpret_cast<float2*>(out + (size_t)node * 128 + lane * 2) = r;
  } else {
    float a = 0.f;
    int j = beg;
    for (; j + 1 < end; j += 2) {
      int s0 = csr_src[j], s1 = csr_src[j + 1];
      float w0 = csr_norm[j], w1 = csr_norm[j + 1];
      a += w0 * h[(size_t)s0 * 64 + lane] + w1 * h[(size_t)s1 * 64 + lane];
    }
    if (j < end) a += csr_norm[j] * h[(size_t)csr_src[j] * 64 + lane];
    out[(size_t)node * 64 + lane] = a;
  }
}

// fused 3-source GEMM: C[n][OUTC] = S0@Weff[0] + S1@Weff[1] + S2@Weff[2] + beff, optional ReLU
// 64 nodes x 64 cols per block; 256 threads, each computes 4x4
template <int INF, int OUTC, bool RELU>
__global__ __launch_bounds__(256) void k_gemm(const float* __restrict__ S0,
                                              const float* __restrict__ S1,
                                              const float* __restrict__ S2,
                                              const float* __restrict__ Weff,
                                              const float* __restrict__ beff,
                                              float* __restrict__ C, int n) {
  __shared__ float XT[32][68];  // [kk][node], padded for alignment/banks
  __shared__ float WS[32][68];  // [kk][col]
  const int tid = threadIdx.x;
  const int n0 = blockIdx.x * 64;
  const int cc = (tid & 15) * 4;
  const int rr = (tid >> 4) * 4;
  const int snode = n0 + (tid >> 2);
  const int foct = (tid & 3) * 8;
  float acc[4][4] = {{0.f}};
  for (int k0 = 0; k0 < 3 * INF; k0 += 32) {
    const int a = k0 / INF;
    const int f0 = k0 % INF;
    const float* sb = (a == 0) ? S0 : (a == 1) ? S1 : S2;
    float4 v0 = make_float4(0.f, 0.f, 0.f, 0.f);
    float4 v1 = make_float4(0.f, 0.f, 0.f, 0.f);
    if (snode < n) {
      const float* sp = sb + (size_t)snode * INF + f0 + foct;
      v0 = *reinterpret_cast<const float4*>(sp);
      v1 = *reinterpret_cast<const float4*>(sp + 4);
    }
    XT[foct + 0][tid >> 2] = v0.x;
    XT[foct + 1][tid >> 2] = v0.y;
    XT[foct + 2][tid >> 2] = v0.z;
    XT[foct + 3][tid >> 2] = v0.w;
    XT[foct + 4][tid >> 2] = v1.x;
    XT[foct + 5][tid >> 2] = v1.y;
    XT[foct + 6][tid >> 2] = v1.z;
    XT[foct + 7][tid >> 2] = v1.w;
    const float* wp = Weff + (size_t)k0 * 64 + tid * 8;
    float4 w0 = *reinterpret_cast<const float4*>(wp);
    float4 w1 = *reinterpret_cast<const float4*>(wp + 4);
    *reinterpret_cast<float4*>(&WS[tid >> 3][(tid & 7) * 8]) = w0;
    *reinterpret_cast<float4*>(&WS[tid >> 3][(tid & 7) * 8 + 4]) = w1;
    __syncthreads();
#pragma unroll
    for (int kk = 0; kk < 32; kk++) {
      float4 xv = *reinterpret_cast<const float4*>(&XT[kk][rr]);
      float4 wv = *reinterpret_cast<const float4*>(&WS[kk][cc]);
      acc[0][0] += xv.x * wv.x; acc[0][1] += xv.x * wv.y; acc[0][2] += xv.x * wv.z; acc[0][3] += xv.x * wv.w;
      acc[1][0] += xv.y * wv.x; acc[1][1] += xv.y * wv.y; acc[1][2] += xv.y * wv.z; acc[1][3] += xv.y * wv.w;
      acc[2][0] += xv.z * wv.x; acc[2][1] += xv.z * wv.y; acc[2][2] += xv.z * wv.z; acc[2][3] += xv.z * wv.w;
      acc[3][0] += xv.w * wv.x; acc[3][1] += xv.w * wv.y; acc[3][2] += xv.w * wv.z; acc[3][3] += xv.w * wv.w;
    }
    __syncthreads();
  }
  if (OUTC == 64 || cc < OUTC) {
    float4 bv = *reinterpret_cast<const float4*>(&beff[cc]);
#pragma unroll
    for (int i = 0; i < 4; i++) {
      int node = n0 + rr + i;
      if (node < n) {
        float4 o;
        o.x = acc[i][0] + bv.x;
        o.y = acc[i][1] + bv.y;
        o.z = acc[i][2] + bv.z;
        o.w = acc[i][3] + bv.w;
        if (RELU) {
          o.x = fmaxf(o.x, 0.f);
          o.y = fmaxf(o.y, 0.f);
          o.z = fmaxf(o.z, 0.f);
          o.w = fmaxf(o.w, 0.f);
        }
        *reinterpret_cast<float4*>(&C[(size_t)node * OUTC + cc]) = o;
      }
    }
  }
}

extern "C" void kernel_launch(void* const* d_in, const int* in_sizes, int n_in,
                              void* d_out, int out_size, void* d_ws, size_t ws_size,
                              hipStream_t stream) {
  const float* x  = (const float*)d_in[0];
  const int*   ei = (const int*)d_in[1];
  const float* W1 = (const float*)d_in[2];
  const float* b1 = (const float*)d_in[3];
  const float* W2 = (const float*)d_in[4];
  const float* b2 = (const float*)d_in[5];
  float* out = (float*)d_out;

  const int N = in_sizes[0] / 128;
  const int E = in_sizes[1] / 2;
  const int* src = ei;
  const int* dst = ei + E;

  // workspace carve-out (256B aligned). Total ~137 MiB for N=100k, E=1.6M.
  char* p = (char*)d_ws;
  size_t used = 0;
  auto alloc = [&](size_t bytes) -> void* {
    void* r = p + used;
    used += (bytes + 255) & ~(size_t)255;
    return r;
  };
  int*   deg      = (int*)alloc((size_t)N * 4);
  int*   indeg    = (int*)alloc((size_t)N * 4);
  float* dinv     = (float*)alloc((size_t)N * 4);
  int*   row_ptr  = (int*)alloc((size_t)(N + 1) * 4);
  int*   pos      = (int*)alloc((size_t)N * 4);
  int*   bsum     = (int*)alloc(256 * 4);
  int*   csr_src  = (int*)alloc((size_t)E * 4);
  float* csr_norm = (float*)alloc((size_t)E * 4);
  float* Weff1    = (float*)alloc(3 * 128 * 64 * 4);
  float* beff1    = (float*)alloc(64 * 4);
  float* Weff2    = (float*)alloc(3 * 64 * 64 * 4);
  float* beff2    = (float*)alloc(64 * 4);
  float* bufA     = (float*)alloc((size_t)N * 128 * 4);
  float* bufB     = (float*)alloc((size_t)N * 128 * 4);
  float* bufH     = (float*)alloc((size_t)N * 64 * 4);
  if (used > ws_size) return;  // clean fail instead of corruption

  hipMemsetAsync(deg, 0, (size_t)N * 4, stream);
  hipMemsetAsync(indeg, 0, (size_t)N * 4, stream);

  const int eb = (E + 255) / 256;
  const int nb = (N + 255) / 256;
  const int sb = (N + 1023) / 1024;

  k_count<<<eb, 256, 0, stream>>>(src, dst, E, deg, indeg);
  k_dinv<<<nb, 256, 0, stream>>>(deg, dinv, N);
  k_scan1<<<sb, 256, 0, stream>>>(indeg, N, row_ptr, bsum);
  k_scan2<<<1, 256, 0, stream>>>(bsum, sb);
  k_scan3<<<(N + 1 + 255) / 256, 256, 0, stream>>>(row_ptr, N, bsum, pos, E);
  k_scatter<<<eb, 256, 0, stream>>>(src, dst, E, dinv, pos, csr_src, csr_norm);

  k_weff<<<(3 * 128 * 64 + 255) / 256, 256, 0, stream>>>(W1, b1, Weff1, beff1, 128, 64);
  k_weff<<<(3 * 64 * 64 + 255) / 256, 256, 0, stream>>>(W2, b2, Weff2, beff2, 64, 40);

  const int pb = ((size_t)N * 64 + 255) / 256;  // wave per node
  const int gb = (N + 63) / 64;

  // layer 1: Tx1 = prop(x); P = prop(Tx1); h = relu(x@(W0-W2) + Tx1@W1 + P@(2W2) + b1)
  k_prop<128><<<pb, 256, 0, stream>>>(x, csr_src, csr_norm, row_ptr, bufA, N);
  k_prop<128><<<pb, 256, 0, stream>>>(bufA, csr_src, csr_norm, row_ptr, bufB, N);
  k_gemm<128, 64, true><<<gb, 256, 0, stream>>>(x, bufA, bufB, Weff1, beff1, bufH, N);

  // layer 2: T1 = prop(h); P = prop(T1); out = h@(W0-W2) + T1@W1 + P@(2W2) + b2
  k_prop<64><<<pb, 256, 0, stream>>>(bufH, csr_src, csr_norm, row_ptr, bufA, N);
  k_prop<64><<<pb, 256, 0, stream>>>(bufA, csr_src, csr_norm, row_ptr, bufB, N);
  k_gemm<64, 40, false><<<gb, 256, 0, stream>>>(bufH, bufA, bufB, Weff2, beff2, out, N);
}

// Round 2
// 648.131 us; speedup vs baseline: 1.2407x; 1.2407x over previous
//
#include <hip/hip_runtime.h>

// ChebConv x2: N=100000, E=1600000, K=3, IN=128, HID=64, OUT=40
// Round 2 strategy:
//   out = x@We0 + L(x@We1) + L(L(x@We2))   (prop and feature-GEMM commute)
//   -> transform FIRST (GEMM 128->192), then propagate at width 64 (layer1)
//      and width 40 (layer2) instead of 128/64. Adds/bias/ReLU fused into
//      prop epilogues. Edge loop unrolled x4 for memory-level parallelism.

__global__ void k_count(const int* __restrict__ src, const int* __restrict__ dst, int E,
                        int* __restrict__ deg, int* __restrict__ indeg) {
  int e = blockIdx.x * blockDim.x + threadIdx.x;
  if (e < E) {
    atomicAdd(&deg[src[e]], 1);
    atomicAdd(&indeg[dst[e]], 1);
  }
}

__global__ void k_dinv(const int* __restrict__ deg, float* __restrict__ dinv, int n) {
  int i = blockIdx.x * blockDim.x + threadIdx.x;
  if (i < n) {
    int d = deg[i];
    dinv[i] = (d > 0) ? rsqrtf((float)d) : 0.f;
  }
}

// exclusive scan phase 1: 1024 elements per block (256 threads x 4)
__global__ void k_scan1(const int* __restrict__ in, int n, int* __restrict__ out,
                        int* __restrict__ bsum) {
  __shared__ int sh[256];
  const int t = threadIdx.x;
  const int base = blockIdx.x * 1024;
  int v[4];
  int s = 0;
#pragma unroll
  for (int i = 0; i < 4; i++) {
    int idx = base + t * 4 + i;
    v[i] = (idx < n) ? in[idx] : 0;
    s += v[i];
  }
  int run = s;
  sh[t] = run;
  __syncthreads();
  for (int off = 1; off < 256; off <<= 1) {
    int x = (t >= off) ? sh[t - off] : 0;
    __syncthreads();
    run += x;
    sh[t] = run;
    __syncthreads();
  }
  if (t == 255) bsum[blockIdx.x] = run;
  int p = run - s;
#pragma unroll
  for (int i = 0; i < 4; i++) {
    int idx = base + t * 4 + i;
    if (idx < n) out[idx] = p;
    p += v[i];
  }
}

__global__ void k_scan2(int* __restrict__ bsum, int nb) {
  __shared__ int sh[256];
  const int t = threadIdx.x;
  int v = (t < nb) ? bsum[t] : 0;
  int run = v;
  sh[t] = run;
  __syncthreads();
  for (int off = 1; off < 256; off <<= 1) {
    int x = (t >= off) ? sh[t - off] : 0;
    __syncthreads();
    run += x;
    sh[t] = run;
    __syncthreads();
  }
  if (t < nb) bsum[t] = run - v;
}

__global__ void k_scan3(int* __restrict__ row_ptr, int n, const int* __restrict__ bsum,
                        int* __restrict__ pos, int Etot) {
  int i = blockIdx.x * blockDim.x + threadIdx.x;
  if (i < n) {
    int v = row_ptr[i] + bsum[i >> 10];
    row_ptr[i] = v;
    pos[i] = v;
  }
  if (i == n) row_ptr[n] = Etot;
}

__global__ void k_scatter(const int* __restrict__ src, const int* __restrict__ dst, int E,
                          const float* __restrict__ dinv, int* __restrict__ pos,
                          int* __restrict__ csr_src, float* __restrict__ csr_norm) {
  int e = blockIdx.x * blockDim.x + threadIdx.x;
  if (e >= E) return;
  int s = src[e], d = dst[e];
  float nm = -dinv[s] * dinv[d];
  int idx = atomicAdd(&pos[d], 1);
  csr_src[idx] = s;
  csr_norm[idx] = nm;
}

// padded effective weights, column chunks [We0 | We1 | We2 | 0-pad]
// We0 = W0 - W2, We1 = W1, We2 = 2*W2.  Wp is [INF][COLS].
__global__ void k_weffp(const float* __restrict__ W, float* __restrict__ Wp,
                        int INF, int OUTC, int COLS) {
  int i = blockIdx.x * blockDim.x + threadIdx.x;
  int total = INF * COLS;
  if (i >= total) return;
  int r = i / COLS;
  int c = i - r * COLS;
  int m = c / OUTC;
  int o = c - m * OUTC;
  float v = 0.f;
  if (m == 0)      v = W[(0 * INF + r) * OUTC + o] - W[(2 * INF + r) * OUTC + o];
  else if (m == 1) v = W[(1 * INF + r) * OUTC + o];
  else if (m == 2) v = 2.f * W[(2 * INF + r) * OUTC + o];
  Wp[i] = v;
}

// wave-per-node CSR propagation, width W, unroll-4, fused add/bias/relu:
//   out[node][0..W) = act( add[node] + (bias) + sum_j norm[j]*g[src[j]][0..W) )
template <int W, bool RELU, bool BIAS>
__global__ __launch_bounds__(256) void k_prop2(const float* __restrict__ g, int gstride,
                                               const float* __restrict__ addv, int astride,
                                               const float* __restrict__ bias,
                                               const int* __restrict__ csr_src,
                                               const float* __restrict__ csr_norm,
                                               const int* __restrict__ row_ptr,
                                               float* __restrict__ out, int ostride, int n) {
  const int lane = threadIdx.x & 63;
  const int node = (blockIdx.x * blockDim.x + threadIdx.x) >> 6;
  if (node >= n) return;
  const int beg = row_ptr[node];
  const int end = row_ptr[node + 1];
  if (W == 64 || lane < W) {
    const float* gl = g + lane;
    float a0 = 0.f, a1 = 0.f, a2 = 0.f, a3 = 0.f;
    int j = beg;
    for (; j + 3 < end; j += 4) {
      int s0 = csr_src[j], s1 = csr_src[j + 1], s2 = csr_src[j + 2], s3 = csr_src[j + 3];
      float w0 = csr_norm[j], w1 = csr_norm[j + 1], w2 = csr_norm[j + 2], w3 = csr_norm[j + 3];
      a0 += w0 * gl[s0 * gstride];
      a1 += w1 * gl[s1 * gstride];
      a2 += w2 * gl[s2 * gstride];
      a3 += w3 * gl[s3 * gstride];
    }
    for (; j < end; ++j) a0 += csr_norm[j] * gl[csr_src[j] * gstride];
    float v = (a0 + a1) + (a2 + a3) + addv[node * astride + lane];
    if (BIAS) v += bias[lane];
    if (RELU) v = fmaxf(v, 0.f);
    out[node * ostride + lane] = v;
  }
}

// GEMM: C[64 nodes][COLS] per block = X[64][INF] @ Wp[INF][COLS]
// 256 threads; thread computes 4 rows x (COLS/16) cols.
template <int INF, int COLS>
__global__ __launch_bounds__(256) void k_gemm2(const float* __restrict__ X, int xstride,
                                               const float* __restrict__ Wp,
                                               float* __restrict__ C, int cstride, int n) {
  constexpr int CPT = COLS / 16;      // cols per thread (12 or 8)
  constexpr int C4R = COLS / 4;       // float4s per W row
  __shared__ float XT[32][68];        // [kk][node]
  __shared__ float WS[32][COLS + 8];  // [kk][col]
  const int tid = threadIdx.x;
  const int n0 = blockIdx.x * 64;
  const int rr = (tid >> 4) * 4;
  const int cc = (tid & 15) * CPT;
  const int snode = n0 + (tid >> 2);
  const int foct = (tid & 3) * 8;
  float acc[4][CPT];
#pragma unroll
  for (int i = 0; i < 4; i++)
#pragma unroll
    for (int j = 0; j < CPT; j++) acc[i][j] = 0.f;

  for (int k0 = 0; k0 < INF; k0 += 32) {
    float4 v0 = make_float4(0.f, 0.f, 0.f, 0.f);
    float4 v1 = make_float4(0.f, 0.f, 0.f, 0.f);
    if (snode < n) {
      const float* sp = X + (size_t)snode * xstride + k0 + foct;
      v0 = *reinterpret_cast<const float4*>(sp);
      v1 = *reinterpret_cast<const float4*>(sp + 4);
    }
    XT[foct + 0][tid >> 2] = v0.x;
    XT[foct + 1][tid >> 2] = v0.y;
    XT[foct + 2][tid >> 2] = v0.z;
    XT[foct + 3][tid >> 2] = v0.w;
    XT[foct + 4][tid >> 2] = v1.x;
    XT[foct + 5][tid >> 2] = v1.y;
    XT[foct + 6][tid >> 2] = v1.z;
    XT[foct + 7][tid >> 2] = v1.w;
#pragma unroll
    for (int i = 0; i < (32 * C4R) / 256; i++) {
      int f = tid + i * 256;
      int row = f / C4R;
      int c4 = f - row * C4R;
      float4 wv = *reinterpret_cast<const float4*>(&Wp[(size_t)(k0 + row) * COLS + c4 * 4]);
      *reinterpret_cast<float4*>(&WS[row][c4 * 4]) = wv;
    }
    __syncthreads();
#pragma unroll
    for (int kk = 0; kk < 32; kk++) {
      float4 xv = *reinterpret_cast<const float4*>(&XT[kk][rr]);
#pragma unroll
      for (int j = 0; j < CPT / 4; j++) {
        float4 wv = *reinterpret_cast<const float4*>(&WS[kk][cc + j * 4]);
        acc[0][j * 4 + 0] += xv.x * wv.x; acc[0][j * 4 + 1] += xv.x * wv.y;
        acc[0][j * 4 + 2] += xv.x * wv.z; acc[0][j * 4 + 3] += xv.x * wv.w;
        acc[1][j * 4 + 0] += xv.y * wv.x; acc[1][j * 4 + 1] += xv.y * wv.y;
        acc[1][j * 4 + 2] += xv.y * wv.z; acc[1][j * 4 + 3] += xv.y * wv.w;
        acc[2][j * 4 + 0] += xv.z * wv.x; acc[2][j * 4 + 1] += xv.z * wv.y;
        acc[2][j * 4 + 2] += xv.z * wv.z; acc[2][j * 4 + 3] += xv.z * wv.w;
        acc[3][j * 4 + 0] += xv.w * wv.x; acc[3][j * 4 + 1] += xv.w * wv.y;
        acc[3][j * 4 + 2] += xv.w * wv.z; acc[3][j * 4 + 3] += xv.w * wv.w;
      }
    }
    __syncthreads();
  }
#pragma unroll
  for (int i = 0; i < 4; i++) {
    int node = n0 + rr + i;
    if (node < n) {
#pragma unroll
      for (int j = 0; j < CPT / 4; j++) {
        float4 o;
        o.x = acc[i][j * 4 + 0];
        o.y = acc[i][j * 4 + 1];
        o.z = acc[i][j * 4 + 2];
        o.w = acc[i][j * 4 + 3];
        *reinterpret_cast<float4*>(&C[(size_t)node * cstride + cc + j * 4]) = o;
      }
    }
  }
}

extern "C" void kernel_launch(void* const* d_in, const int* in_sizes, int n_in,
                              void* d_out, int out_size, void* d_ws, size_t ws_size,
                              hipStream_t stream) {
  const float* x  = (const float*)d_in[0];
  const int*   ei = (const int*)d_in[1];
  const float* W1 = (const float*)d_in[2];
  const float* b1 = (const float*)d_in[3];
  const float* W2 = (const float*)d_in[4];
  const float* b2 = (const float*)d_in[5];
  float* out = (float*)d_out;

  const int N = in_sizes[0] / 128;
  const int E = in_sizes[1] / 2;
  const int* src = ei;
  const int* dst = ei + E;

  // workspace carve-out (256B aligned). Peak ~142.9 MiB (== round-1 proven budget).
  char* p = (char*)d_ws;
  size_t used = 0;
  auto alloc = [&](size_t bytes) -> void* {
    void* r = p + used;
    used += (bytes + 255) & ~(size_t)255;
    return r;
  };
  int*   deg      = (int*)alloc((size_t)N * 4);
  int*   indeg    = (int*)alloc((size_t)N * 4);
  float* dinv     = (float*)alloc((size_t)N * 4);
  int*   row_ptr  = (int*)alloc((size_t)(N + 1) * 4);
  int*   pos      = (int*)alloc((size_t)N * 4);
  int*   bsum     = (int*)alloc(256 * 4);
  int*   csr_src  = (int*)alloc((size_t)E * 4);
  float* csr_norm = (float*)alloc((size_t)E * 4);
  float* Wp1      = (float*)alloc((size_t)128 * 192 * 4);
  float* Wp2      = (float*)alloc((size_t)64 * 128 * 4);
  float* regA     = (float*)alloc((size_t)N * 192 * 4);  // Y [N,192]; later Z2 [N,40]
  float* regB     = (float*)alloc((size_t)N * 128 * 4);  // Z [N,64]; later U [N,128]
  if (used > ws_size) return;  // clean fail instead of corruption

  float* Y  = regA;  // [N,192] = [Y0 | Y1->h | Y2]
  float* Z  = regB;  // [N,64]
  float* U  = regB;  // [N,128] = [U0 | U1 | U2 | pad], overwrites dead Z
  float* Z2 = regA;  // [N,40], overwrites dead Y

  hipMemsetAsync(deg, 0, (size_t)N * 4, stream);
  hipMemsetAsync(indeg, 0, (size_t)N * 4, stream);

  const int eb = (E + 255) / 256;
  const int nb = (N + 255) / 256;
  const int sb = (N + 1023) / 1024;

  k_count<<<eb, 256, 0, stream>>>(src, dst, E, deg, indeg);
  k_dinv<<<nb, 256, 0, stream>>>(deg, dinv, N);
  k_scan1<<<sb, 256, 0, stream>>>(indeg, N, row_ptr, bsum);
  k_scan2<<<1, 256, 0, stream>>>(bsum, sb);
  k_scan3<<<(N + 1 + 255) / 256, 256, 0, stream>>>(row_ptr, N, bsum, pos, E);
  k_scatter<<<eb, 256, 0, stream>>>(src, dst, E, dinv, pos, csr_src, csr_norm);

  k_weffp<<<(128 * 192 + 255) / 256, 256, 0, stream>>>(W1, Wp1, 128, 64, 192);
  k_weffp<<<(64 * 128 + 255) / 256, 256, 0, stream>>>(W2, Wp2, 64, 40, 128);

  const int pb = ((size_t)N * 64 + 255) / 256;  // wave per node
  const int gb = (N + 63) / 64;

  // layer 1: Y = x @ [We0|We1|We2]; Z = Y1 + L*Y2; h = relu(Y0 + L*Z + b1)
  k_gemm2<128, 192><<<gb, 256, 0, stream>>>(x, 128, Wp1, Y, 192, N);
  k_prop2<64, false, false><<<pb, 256, 0, stream>>>(Y + 128, 192, Y + 64, 192, nullptr,
                                                    csr_src, csr_norm, row_ptr, Z, 64, N);
  // h written into Y's dead Y1 columns (each node writes only its own row)
  k_prop2<64, true, true><<<pb, 256, 0, stream>>>(Z, 64, Y, 192, b1,
                                                  csr_src, csr_norm, row_ptr, Y + 64, 192, N);
  // layer 2: U = h @ [Ve0|Ve1|Ve2|0]; Z2 = U1 + L*U2; out = U0 + L*Z2 + b2
  k_gemm2<64, 128><<<gb, 256, 0, stream>>>(Y + 64, 192, Wp2, U, 128, N);
  k_prop2<40, false, false><<<pb, 256, 0, stream>>>(U + 80, 128, U + 40, 128, nullptr,
                                                    csr_src, csr_norm, row_ptr, Z2, 40, N);
  k_prop2<40, false, true><<<pb, 256, 0, stream>>>(Z2, 40, U, 128, b2,
                                                   csr_src, csr_norm, row_ptr, out, 40, N);
}

// Round 3
// 518.407 us; speedup vs baseline: 1.5512x; 1.2502x over previous
//
#include <hip/hip_runtime.h>

// ChebConv x2: N=100000, E=1600000, K=3, IN=128, HID=64, OUT=40
// Round 3:
//  - norm array eliminated: prop(h)[d] = -dinv[d] * sum_s dinv[s]*h[s];
//    inputs pre-scaled by dinv in producer epilogues, output scaled in prop.
//  - CSR build via bucket radix (dst>>7 buckets, LDS histograms + LDS cursors):
//    only remaining global atomics are the 1.6M byte-packed deg[src] counts.
//  - props unroll x8, compile-time gather strides.

#define NBLK_PART 256
#define MAXBUK 1024

// pass A: deg byte-histogram (global atomics, 4 counters/word) + per-block
// bucket histogram of dst>>7
__global__ __launch_bounds__(256) void k_passA(const int* __restrict__ src,
                                               const int* __restrict__ dst, int E, int cpb,
                                               unsigned int* __restrict__ degpk,
                                               int* __restrict__ histG, int nbuk) {
  __shared__ int hist[MAXBUK];
  const int t = threadIdx.x, b = blockIdx.x;
  for (int k = t; k < nbuk; k += 256) hist[k] = 0;
  __syncthreads();
  const int e0 = b * cpb;
  const int e1 = min(E, e0 + cpb);
  for (int e = e0 + t; e < e1; e += 256) {
    int s = src[e], d = dst[e];
    atomicAdd(&degpk[s >> 2], 1u << ((s & 3) * 8));  // max degree << 255
    atomicAdd(&hist[d >> 7], 1);
  }
  __syncthreads();
  for (int k = t; k < nbuk; k += 256) histG[k * NBLK_PART + b] = hist[k];
}

__global__ void k_dinv(const unsigned int* __restrict__ degpk, float* __restrict__ dinv,
                       int n) {
  int i = blockIdx.x * blockDim.x + threadIdx.x;
  if (i < n) {
    int d = (degpk[i >> 2] >> ((i & 3) * 8)) & 255;
    dinv[i] = (d > 0) ? rsqrtf((float)d) : 0.f;
  }
}

// per bucket: exclusive scan over the 256 partition blocks
__global__ __launch_bounds__(256) void k_scanA(int* __restrict__ histG,
                                               int* __restrict__ buktot) {
  __shared__ int sh[256];
  const int b = blockIdx.x, t = threadIdx.x;
  int v = histG[b * NBLK_PART + t];
  int run = v;
  sh[t] = run;
  __syncthreads();
  for (int off = 1; off < 256; off <<= 1) {
    int x = (t >= off) ? sh[t - off] : 0;
    __syncthreads();
    run += x;
    sh[t] = run;
    __syncthreads();
  }
  if (t == 255) buktot[b] = run;
  histG[b * NBLK_PART + t] = run - v;
}

// single-block exclusive scan in place, nb <= 1024
__global__ __launch_bounds__(256) void k_scanB(int* __restrict__ a, int nb) {
  __shared__ int sh[256];
  const int t = threadIdx.x;
  int v[4];
  int s = 0;
#pragma unroll
  for (int i = 0; i < 4; i++) {
    int idx = t * 4 + i;
    v[i] = (idx < nb) ? a[idx] : 0;
    s += v[i];
  }
  int run = s;
  sh[t] = run;
  __syncthreads();
  for (int off = 1; off < 256; off <<= 1) {
    int x = (t >= off) ? sh[t - off] : 0;
    __syncthreads();
    run += x;
    sh[t] = run;
    __syncthreads();
  }
  int p = run - s;
#pragma unroll
  for (int i = 0; i < 4; i++) {
    int idx = t * 4 + i;
    if (idx < nb) a[idx] = p;
    p += v[i];
  }
}

// pass B: scatter edges into bucket-grouped order, packed (src<<7)|(dst&127)
__global__ __launch_bounds__(256) void k_passB(const int* __restrict__ src,
                                               const int* __restrict__ dst, int E, int cpb,
                                               const int* __restrict__ histG,
                                               const int* __restrict__ bukoff, int nbuk,
                                               unsigned int* __restrict__ packed) {
  __shared__ int cur[MAXBUK];
  const int t = threadIdx.x, b = blockIdx.x;
  for (int k = t; k < nbuk; k += 256) cur[k] = bukoff[k] + histG[k * NBLK_PART + b];
  __syncthreads();
  const int e0 = b * cpb;
  const int e1 = min(E, e0 + cpb);
  for (int e = e0 + t; e < e1; e += 256) {
    int s = src[e], d = dst[e];
    int slot = atomicAdd(&cur[d >> 7], 1);
    packed[slot] = ((unsigned)s << 7) | (unsigned)(d & 127);
  }
}

// pass C: per-bucket (128 nodes) CSR finalize fully in LDS
__global__ __launch_bounds__(256) void k_passC(const unsigned int* __restrict__ packed,
                                               const int* __restrict__ bukoff, int nbuk,
                                               int E, int n, int* __restrict__ csr_src,
                                               int* __restrict__ row_ptr) {
  __shared__ int cnt[128], scn[128], cur[128];
  const int t = threadIdx.x, b = blockIdx.x;
  if (t < 128) cnt[t] = 0;
  __syncthreads();
  const int e0 = bukoff[b];
  const int e1 = (b + 1 < nbuk) ? bukoff[b + 1] : E;
  for (int e = e0 + t; e < e1; e += 256) atomicAdd(&cnt[packed[e] & 127], 1);
  __syncthreads();
  if (t < 128) scn[t] = cnt[t];
  __syncthreads();
  for (int off = 1; off < 128; off <<= 1) {
    int x = (t < 128 && t >= off) ? scn[t - off] : 0;
    __syncthreads();
    if (t < 128) scn[t] += x;
    __syncthreads();
  }
  if (t < 128) {
    int start = e0 + scn[t] - cnt[t];
    cur[t] = start;
    int node = (b << 7) + t;
    if (node < n) row_ptr[node] = start;
  }
  if (b == 0 && t == 0) row_ptr[n] = E;
  __syncthreads();
  for (int e = e0 + t; e < e1; e += 256) {
    unsigned v = packed[e];
    int slot = atomicAdd(&cur[v & 127], 1);
    csr_src[slot] = (int)(v >> 7);
  }
}

// padded effective weights, column chunks [We0 | We1 | We2 | 0-pad]
__global__ void k_weffp(const float* __restrict__ W, float* __restrict__ Wp,
                        int INF, int OUTC, int COLS) {
  int i = blockIdx.x * blockDim.x + threadIdx.x;
  int total = INF * COLS;
  if (i >= total) return;
  int r = i / COLS;
  int c = i - r * COLS;
  int m = c / OUTC;
  int o = c - m * OUTC;
  float v = 0.f;
  if (m == 0)      v = W[(0 * INF + r) * OUTC + o] - W[(2 * INF + r) * OUTC + o];
  else if (m == 1) v = W[(1 * INF + r) * OUTC + o];
  else if (m == 2) v = 2.f * W[(2 * INF + r) * OUTC + o];
  Wp[i] = v;
}

// wave-per-node CSR propagation, unroll-8, norm-free:
//   G = sum_j g[src[j]] (g pre-scaled by dinv[s]); v = addv - dinv[d]*G (+bias)
//   optional output scale by dinv[d] (for chained props) and ReLU
template <int W, int GS, bool RELU, bool BIAS, bool OUTSCALE>
__global__ __launch_bounds__(256) void k_prop3(const float* __restrict__ g,
                                               const float* __restrict__ addv, int astride,
                                               const float* __restrict__ bias,
                                               const float* __restrict__ dinv,
                                               const int* __restrict__ csr_src,
                                               const int* __restrict__ row_ptr,
                                               float* __restrict__ out, int ostride, int n) {
  const int lane = threadIdx.x & 63;
  const int node = (blockIdx.x * blockDim.x + threadIdx.x) >> 6;
  if (node >= n) return;
  const int beg = row_ptr[node];
  const int end = row_ptr[node + 1];
  const float dv = dinv[node];
  if (W == 64 || lane < W) {
    const float* gl = g + lane;
    float a0 = 0.f, a1 = 0.f, a2 = 0.f, a3 = 0.f, a4 = 0.f, a5 = 0.f, a6 = 0.f, a7 = 0.f;
    int j = beg;
    for (; j + 7 < end; j += 8) {
      int s0 = csr_src[j], s1 = csr_src[j + 1], s2 = csr_src[j + 2], s3 = csr_src[j + 3];
      int s4 = csr_src[j + 4], s5 = csr_src[j + 5], s6 = csr_src[j + 6], s7 = csr_src[j + 7];
      a0 += gl[(size_t)s0 * GS];
      a1 += gl[(size_t)s1 * GS];
      a2 += gl[(size_t)s2 * GS];
      a3 += gl[(size_t)s3 * GS];
      a4 += gl[(size_t)s4 * GS];
      a5 += gl[(size_t)s5 * GS];
      a6 += gl[(size_t)s6 * GS];
      a7 += gl[(size_t)s7 * GS];
    }
    for (; j < end; ++j) a0 += gl[(size_t)csr_src[j] * GS];
    float G = ((a0 + a1) + (a2 + a3)) + ((a4 + a5) + (a6 + a7));
    float v = addv[(size_t)node * astride + lane] - dv * G;
    if (BIAS) v += bias[lane];
    if (OUTSCALE) v *= dv;
    if (RELU) v = fmaxf(v, 0.f);
    out[(size_t)node * ostride + lane] = v;
  }
}

// GEMM: C[64 nodes][COLS] = X[64][INF] @ Wp[INF][COLS]; cols in [SCLO,SCHI)
// scaled by dinv[node] (pre-scaling the next prop's gather input for free)
template <int INF, int COLS, int SCLO, int SCHI>
__global__ __launch_bounds__(256) void k_gemm3(const float* __restrict__ X, int xstride,
                                               const float* __restrict__ Wp,
                                               const float* __restrict__ dinv,
                                               float* __restrict__ C, int cstride, int n) {
  constexpr int CPT = COLS / 16;
  constexpr int C4R = COLS / 4;
  __shared__ float XT[32][68];
  __shared__ float WS[32][COLS + 8];
  const int tid = threadIdx.x;
  const int n0 = blockIdx.x * 64;
  const int rr = (tid >> 4) * 4;
  const int cc = (tid & 15) * CPT;
  const int snode = n0 + (tid >> 2);
  const int foct = (tid & 3) * 8;
  float acc[4][CPT];
#pragma unroll
  for (int i = 0; i < 4; i++)
#pragma unroll
    for (int j = 0; j < CPT; j++) acc[i][j] = 0.f;

  for (int k0 = 0; k0 < INF; k0 += 32) {
    float4 v0 = make_float4(0.f, 0.f, 0.f, 0.f);
    float4 v1 = make_float4(0.f, 0.f, 0.f, 0.f);
    if (snode < n) {
      const float* sp = X + (size_t)snode * xstride + k0 + foct;
      v0 = *reinterpret_cast<const float4*>(sp);
      v1 = *reinterpret_cast<const float4*>(sp + 4);
    }
    XT[foct + 0][tid >> 2] = v0.x;
    XT[foct + 1][tid >> 2] = v0.y;
    XT[foct + 2][tid >> 2] = v0.z;
    XT[foct + 3][tid >> 2] = v0.w;
    XT[foct + 4][tid >> 2] = v1.x;
    XT[foct + 5][tid >> 2] = v1.y;
    XT[foct + 6][tid >> 2] = v1.z;
    XT[foct + 7][tid >> 2] = v1.w;
#pragma unroll
    for (int i = 0; i < (32 * C4R) / 256; i++) {
      int f = tid + i * 256;
      int row = f / C4R;
      int c4 = f - row * C4R;
      float4 wv = *reinterpret_cast<const float4*>(&Wp[(size_t)(k0 + row) * COLS + c4 * 4]);
      *reinterpret_cast<float4*>(&WS[row][c4 * 4]) = wv;
    }
    __syncthreads();
#pragma unroll
    for (int kk = 0; kk < 32; kk++) {
      float4 xv = *reinterpret_cast<const float4*>(&XT[kk][rr]);
#pragma unroll
      for (int j = 0; j < CPT / 4; j++) {
        float4 wv = *reinterpret_cast<const float4*>(&WS[kk][cc + j * 4]);
        acc[0][j * 4 + 0] += xv.x * wv.x; acc[0][j * 4 + 1] += xv.x * wv.y;
        acc[0][j * 4 + 2] += xv.x * wv.z; acc[0][j * 4 + 3] += xv.x * wv.w;
        acc[1][j * 4 + 0] += xv.y * wv.x; acc[1][j * 4 + 1] += xv.y * wv.y;
        acc[1][j * 4 + 2] += xv.y * wv.z; acc[1][j * 4 + 3] += xv.y * wv.w;
        acc[2][j * 4 + 0] += xv.z * wv.x; acc[2][j * 4 + 1] += xv.z * wv.y;
        acc[2][j * 4 + 2] += xv.z * wv.z; acc[2][j * 4 + 3] += xv.z * wv.w;
        acc[3][j * 4 + 0] += xv.w * wv.x; acc[3][j * 4 + 1] += xv.w * wv.y;
        acc[3][j * 4 + 2] += xv.w * wv.z; acc[3][j * 4 + 3] += xv.w * wv.w;
      }
    }
    __syncthreads();
  }
#pragma unroll
  for (int i = 0; i < 4; i++) {
    int node = n0 + rr + i;
    if (node < n) {
      float dv = dinv[node];
#pragma unroll
      for (int j = 0; j < CPT / 4; j++) {
        int cb = cc + j * 4;
        float4 o;
        o.x = acc[i][j * 4 + 0] * ((cb + 0 >= SCLO && cb + 0 < SCHI) ? dv : 1.f);
        o.y = acc[i][j * 4 + 1] * ((cb + 1 >= SCLO && cb + 1 < SCHI) ? dv : 1.f);
        o.z = acc[i][j * 4 + 2] * ((cb + 2 >= SCLO && cb + 2 < SCHI) ? dv : 1.f);
        o.w = acc[i][j * 4 + 3] * ((cb + 3 >= SCLO && cb + 3 < SCHI) ? dv : 1.f);
        *reinterpret_cast<float4*>(&C[(size_t)node * cstride + cb]) = o;
      }
    }
  }
}

extern "C" void kernel_launch(void* const* d_in, const int* in_sizes, int n_in,
                              void* d_out, int out_size, void* d_ws, size_t ws_size,
                              hipStream_t stream) {
  const float* x  = (const float*)d_in[0];
  const int*   ei = (const int*)d_in[1];
  const float* W1 = (const float*)d_in[2];
  const float* b1 = (const float*)d_in[3];
  const float* W2 = (const float*)d_in[4];
  const float* b2 = (const float*)d_in[5];
  float* out = (float*)d_out;

  const int N = in_sizes[0] / 128;
  const int E = in_sizes[1] / 2;
  const int* src = ei;
  const int* dst = ei + E;

  const int nbuk = (N + 127) >> 7;
  if (nbuk > MAXBUK) return;
  const int cpb = (E + NBLK_PART - 1) / NBLK_PART;

  char* p = (char*)d_ws;
  size_t used = 0;
  auto alloc = [&](size_t bytes) -> void* {
    void* r = p + used;
    used += (bytes + 255) & ~(size_t)255;
    return r;
  };
  unsigned int* degpk = (unsigned int*)alloc((size_t)((N + 3) / 4) * 4);
  float* dinv    = (float*)alloc((size_t)N * 4);
  int*   row_ptr = (int*)alloc((size_t)(N + 1) * 4);
  int*   csr_src = (int*)alloc((size_t)E * 4);
  int*   buktot  = (int*)alloc((size_t)MAXBUK * 4);
  float* Wp1     = (float*)alloc((size_t)128 * 192 * 4);
  float* Wp2     = (float*)alloc((size_t)64 * 128 * 4);
  float* regA    = (float*)alloc((size_t)N * 192 * 4);  // Y; later Z2s
  float* regB    = (float*)alloc((size_t)N * 128 * 4);  // Zs; later U
  if (used > ws_size) return;

  // radix temporaries alias regA (dead until gemm1)
  unsigned int* packed = (unsigned int*)regA;                          // E*4 = 6.4 MB
  int* histG = (int*)((char*)regA + ((size_t)E * 4 + 4096 + 255 & ~(size_t)255));  // nbuk*256*4

  float* Y   = regA;  // [N,192] = [Y0 | Y1->h | Ys2]
  float* Zs  = regB;  // [N,64]
  float* U   = regB;  // [N,128] = [U0 | U1 | Us2 | pad]
  float* Z2s = regA;  // [N,40]

  hipMemsetAsync(degpk, 0, (size_t)((N + 3) / 4) * 4, stream);

  k_passA<<<NBLK_PART, 256, 0, stream>>>(src, dst, E, cpb, degpk, histG, nbuk);
  k_dinv<<<(N + 255) / 256, 256, 0, stream>>>(degpk, dinv, N);
  k_scanA<<<nbuk, 256, 0, stream>>>(histG, buktot);
  k_scanB<<<1, 256, 0, stream>>>(buktot, nbuk);
  k_passB<<<NBLK_PART, 256, 0, stream>>>(src, dst, E, cpb, histG, buktot, nbuk, packed);
  k_passC<<<nbuk, 256, 0, stream>>>(packed, buktot, nbuk, E, N, csr_src, row_ptr);

  k_weffp<<<(128 * 192 + 255) / 256, 256, 0, stream>>>(W1, Wp1, 128, 64, 192);
  k_weffp<<<(64 * 128 + 255) / 256, 256, 0, stream>>>(W2, Wp2, 64, 40, 128);

  const int pb = ((size_t)N * 64 + 255) / 256;
  const int gb = (N + 63) / 64;

  // layer 1: Y = x@[We0|We1|dinv*We2-col]; Zs = dinv*(Y1 - dinv*G(Ys2));
  //          h = relu(Y0 - dinv*G(Zs) + b1) written into Y1's columns
  k_gemm3<128, 192, 128, 192><<<gb, 256, 0, stream>>>(x, 128, Wp1, dinv, Y, 192, N);
  k_prop3<64, 192, false, false, true><<<pb, 256, 0, stream>>>(
      Y + 128, Y + 64, 192, nullptr, dinv, csr_src, row_ptr, Zs, 64, N);
  k_prop3<64, 64, true, true, false><<<pb, 256, 0, stream>>>(
      Zs, Y, 192, b1, dinv, csr_src, row_ptr, Y + 64, 192, N);
  // layer 2: U = h@[Ve0|Ve1|dinv*Ve2|0]; Z2s = dinv*(U1 - dinv*G(Us2));
  //          out = U0 - dinv*G(Z2s) + b2
  k_gemm3<64, 128, 80, 120><<<gb, 256, 0, stream>>>(Y + 64, 192, Wp2, dinv, U, 128, N);
  k_prop3<40, 128, false, false, true><<<pb, 256, 0, stream>>>(
      U + 80, U + 40, 128, nullptr, dinv, csr_src, row_ptr, Z2s, 40, N);
  k_prop3<40, 40, false, true, false><<<pb, 256, 0, stream>>>(
      Z2s, U, 128, b2, dinv, csr_src, row_ptr, out, 40, N);
}

// Round 4
// 485.589 us; speedup vs baseline: 1.6561x; 1.0676x over previous
//
#include <hip/hip_runtime.h>

// ChebConv x2: N=100000, E=1600000, K=3, IN=128, HID=64, OUT=40
// Round 4:
//  - GEMMs via bf16 MFMA (16x16x32): X staged fp32->bf16 in LDS, W pre-swizzled
//    into per-fragment coalesced order (bf16), dinv col-scaling in epilogue.
//  - radix passes at 1024 blocks for atomic-latency hiding.
//  - props (norm-free, unroll-8) unchanged from round 3.

#define NBLK_PART 1024
#define MAXBUK 1024

typedef __attribute__((ext_vector_type(8))) short bf16x8;
typedef __attribute__((ext_vector_type(4))) float f32x4;

__device__ inline unsigned short f2bf(float f) {
  unsigned u = __float_as_uint(f);
  return (unsigned short)((u + 0x7FFFu + ((u >> 16) & 1u)) >> 16);
}
__device__ inline unsigned pk2(float a, float b) {
  return (unsigned)f2bf(a) | ((unsigned)f2bf(b) << 16);
}

// pass A: byte-packed deg[src] atomics + per-block LDS histogram of dst>>7
__global__ __launch_bounds__(256) void k_passA(const int* __restrict__ src,
                                               const int* __restrict__ dst, int E, int cpb,
                                               unsigned int* __restrict__ degpk,
                                               int* __restrict__ histG, int nbuk) {
  __shared__ int hist[MAXBUK];
  const int t = threadIdx.x, b = blockIdx.x;
  for (int k = t; k < nbuk; k += 256) hist[k] = 0;
  __syncthreads();
  const int e0 = b * cpb;
  const int e1 = min(E, e0 + cpb);
  for (int e = e0 + t; e < e1; e += 256) {
    int s = src[e], d = dst[e];
    atomicAdd(&degpk[s >> 2], 1u << ((s & 3) * 8));  // max degree << 255
    atomicAdd(&hist[d >> 7], 1);
  }
  __syncthreads();
  for (int k = t; k < nbuk; k += 256) histG[k * NBLK_PART + b] = hist[k];
}

__global__ void k_dinv(const unsigned int* __restrict__ degpk, float* __restrict__ dinv,
                       int n) {
  int i = blockIdx.x * blockDim.x + threadIdx.x;
  if (i < n) {
    int d = (degpk[i >> 2] >> ((i & 3) * 8)) & 255;
    dinv[i] = (d > 0) ? rsqrtf((float)d) : 0.f;
  }
}

// per bucket: exclusive scan over the 1024 partition blocks (4 per thread)
__global__ __launch_bounds__(256) void k_scanA(int* __restrict__ histG,
                                               int* __restrict__ buktot) {
  __shared__ int sh[256];
  const int b = blockIdx.x, t = threadIdx.x;
  const int base = b * NBLK_PART;
  int v[4];
  int s = 0;
#pragma unroll
  for (int i = 0; i < 4; i++) {
    v[i] = histG[base + t * 4 + i];
    s += v[i];
  }
  int run = s;
  sh[t] = run;
  __syncthreads();
  for (int off = 1; off < 256; off <<= 1) {
    int x = (t >= off) ? sh[t - off] : 0;
    __syncthreads();
    run += x;
    sh[t] = run;
    __syncthreads();
  }
  if (t == 255) buktot[b] = run;
  int p = run - s;
#pragma unroll
  for (int i = 0; i < 4; i++) {
    histG[base + t * 4 + i] = p;
    p += v[i];
  }
}

// single-block exclusive scan in place, nb <= 1024
__global__ __launch_bounds__(256) void k_scanB(int* __restrict__ a, int nb) {
  __shared__ int sh[256];
  const int t = threadIdx.x;
  int v[4];
  int s = 0;
#pragma unroll
  for (int i = 0; i < 4; i++) {
    int idx = t * 4 + i;
    v[i] = (idx < nb) ? a[idx] : 0;
    s += v[i];
  }
  int run = s;
  sh[t] = run;
  __syncthreads();
  for (int off = 1; off < 256; off <<= 1) {
    int x = (t >= off) ? sh[t - off] : 0;
    __syncthreads();
    run += x;
    sh[t] = run;
    __syncthreads();
  }
  int p = run - s;
#pragma unroll
  for (int i = 0; i < 4; i++) {
    int idx = t * 4 + i;
    if (idx < nb) a[idx] = p;
    p += v[i];
  }
}

// pass B: scatter edges into bucket-grouped order, packed (src<<7)|(dst&127)
__global__ __launch_bounds__(256) void k_passB(const int* __restrict__ src,
                                               const int* __restrict__ dst, int E, int cpb,
                                               const int* __restrict__ histG,
                                               const int* __restrict__ bukoff, int nbuk,
                                               unsigned int* __restrict__ packed) {
  __shared__ int cur[MAXBUK];
  const int t = threadIdx.x, b = blockIdx.x;
  for (int k = t; k < nbuk; k += 256) cur[k] = bukoff[k] + histG[k * NBLK_PART + b];
  __syncthreads();
  const int e0 = b * cpb;
  const int e1 = min(E, e0 + cpb);
  for (int e = e0 + t; e < e1; e += 256) {
    int s = src[e], d = dst[e];
    int slot = atomicAdd(&cur[d >> 7], 1);
    packed[slot] = ((unsigned)s << 7) | (unsigned)(d & 127);
  }
}

// pass C: per-bucket (128 nodes) CSR finalize fully in LDS
__global__ __launch_bounds__(256) void k_passC(const unsigned int* __restrict__ packed,
                                               const int* __restrict__ bukoff, int nbuk,
                                               int E, int n, int* __restrict__ csr_src,
                                               int* __restrict__ row_ptr) {
  __shared__ int cnt[128], scn[128], cur[128];
  const int t = threadIdx.x, b = blockIdx.x;
  if (t < 128) cnt[t] = 0;
  __syncthreads();
  const int e0 = bukoff[b];
  const int e1 = (b + 1 < nbuk) ? bukoff[b + 1] : E;
  for (int e = e0 + t; e < e1; e += 256) atomicAdd(&cnt[packed[e] & 127], 1);
  __syncthreads();
  if (t < 128) scn[t] = cnt[t];
  __syncthreads();
  for (int off = 1; off < 128; off <<= 1) {
    int x = (t < 128 && t >= off) ? scn[t - off] : 0;
    __syncthreads();
    if (t < 128) scn[t] += x;
    __syncthreads();
  }
  if (t < 128) {
    int start = e0 + scn[t] - cnt[t];
    cur[t] = start;
    int node = (b << 7) + t;
    if (node < n) row_ptr[node] = start;
  }
  if (b == 0 && t == 0) row_ptr[n] = E;
  __syncthreads();
  for (int e = e0 + t; e < e1; e += 256) {
    unsigned v = packed[e];
    int slot = atomicAdd(&cur[v & 127], 1);
    csr_src[slot] = (int)(v >> 7);
  }
}

// pre-swizzle effective weights into MFMA B-fragment order, bf16:
// Wfrag[((ks*NT + nt)*64 + lane)*8 + j] = We[k = ks*32 + (lane>>4)*8 + j][col = nt*16 + (lane&15)]
// We0 = W0 - W2, We1 = W1, We2 = 2*W2 (cols beyond 3*OUTC zero)
__global__ void k_wfrag(const float* __restrict__ W, unsigned short* __restrict__ Wfrag,
                        int INF, int OUTC, int NT) {
  int idx = blockIdx.x * 256 + threadIdx.x;
  int total = (INF / 32) * NT * 64;
  if (idx >= total) return;
  int lane = idx & 63;
  int nt = (idx >> 6) % NT;
  int ks = idx / (64 * NT);
  int col = nt * 16 + (lane & 15);
  int kb = ks * 32 + (lane >> 4) * 8;
  unsigned short o8[8];
#pragma unroll
  for (int j = 0; j < 8; j++) {
    int k = kb + j;
    float v = 0.f;
    if (col < 3 * OUTC) {
      int m = col / OUTC, o = col - m * OUTC;
      if (m == 0)      v = W[(0 * INF + k) * OUTC + o] - W[(2 * INF + k) * OUTC + o];
      else if (m == 1) v = W[(1 * INF + k) * OUTC + o];
      else             v = 2.f * W[(2 * INF + k) * OUTC + o];
    }
    o8[j] = f2bf(v);
  }
  uint4 r;
  r.x = (unsigned)o8[0] | ((unsigned)o8[1] << 16);
  r.y = (unsigned)o8[2] | ((unsigned)o8[3] << 16);
  r.z = (unsigned)o8[4] | ((unsigned)o8[5] << 16);
  r.w = (unsigned)o8[6] | ((unsigned)o8[7] << 16);
  *reinterpret_cast<uint4*>(Wfrag + (size_t)idx * 8) = r;
}

// MFMA GEMM: C[64 nodes][NT*16] = bf16(X[64][INF]) @ Wfrag; cols [SCLO,SCHI)
// scaled by dinv[row]. 4 waves, wave w owns nodes [16w,16w+16).
template <int INF, int NT, int XSTR, int SCLO, int SCHI, int OSTR>
__global__ __launch_bounds__(256) void k_gemm_mfma(const float* __restrict__ X,
                                                   const unsigned short* __restrict__ Wfrag,
                                                   const float* __restrict__ dinv,
                                                   float* __restrict__ C, int n) {
  constexpr int KSTEPS = INF / 32;
  constexpr int KP = INF + 8;  // ushorts per LDS row (row stride 16B-aligned, bank-spread)
  __shared__ unsigned short XA[64 * KP];
  const int tid = threadIdx.x;
  const int lane = tid & 63;
  const int w = tid >> 6;
  const int n0 = blockIdx.x * 64;
  // stage X (fp32 global, coalesced) -> bf16 LDS
  {
    const int node = tid >> 2;
    const int k0 = (tid & 3) * (INF / 4);
    const bool ok = (n0 + node) < n;
    const float* sp = X + (size_t)(n0 + node) * XSTR + k0;
    unsigned short* dp = &XA[node * KP + k0];
#pragma unroll
    for (int i = 0; i < INF / 32; i++) {
      float4 va = make_float4(0.f, 0.f, 0.f, 0.f), vb = va;
      if (ok) {
        va = *reinterpret_cast<const float4*>(sp + 8 * i);
        vb = *reinterpret_cast<const float4*>(sp + 8 * i + 4);
      }
      uint4 u;
      u.x = pk2(va.x, va.y);
      u.y = pk2(va.z, va.w);
      u.z = pk2(vb.x, vb.y);
      u.w = pk2(vb.z, vb.w);
      *reinterpret_cast<uint4*>(dp + 8 * i) = u;
    }
  }
  __syncthreads();
  // A fragments for all K-steps (row = lane&15 within wave's 16-node tile)
  bf16x8 afrag[KSTEPS];
  {
    const unsigned short* arow = &XA[(16 * w + (lane & 15)) * KP + (lane >> 4) * 8];
#pragma unroll
    for (int ks = 0; ks < KSTEPS; ks++)
      afrag[ks] = *reinterpret_cast<const bf16x8*>(arow + ks * 32);
  }
  f32x4 acc[NT];
#pragma unroll
  for (int nt = 0; nt < NT; nt++) acc[nt] = (f32x4){0.f, 0.f, 0.f, 0.f};
  const unsigned short* wf = Wfrag + (size_t)lane * 8;
#pragma unroll
  for (int ks = 0; ks < KSTEPS; ks++) {
#pragma unroll
    for (int nt = 0; nt < NT; nt++) {
      bf16x8 b = *reinterpret_cast<const bf16x8*>(wf + (size_t)(ks * NT + nt) * 512);
      acc[nt] = __builtin_amdgcn_mfma_f32_16x16x32_bf16(afrag[ks], b, acc[nt], 0, 0, 0);
    }
  }
  // epilogue: D row = (lane>>4)*4 + r, col = nt*16 + (lane&15)
  const int rq = (lane >> 4) * 4;
#pragma unroll
  for (int r = 0; r < 4; r++) {
    int row = n0 + 16 * w + rq + r;
    if (row < n) {
      float dv = dinv[row];
#pragma unroll
      for (int nt = 0; nt < NT; nt++) {
        int col = nt * 16 + (lane & 15);
        float v = acc[nt][r];
        if (col >= SCLO && col < SCHI) v *= dv;
        C[(size_t)row * OSTR + col] = v;
      }
    }
  }
}

// wave-per-node CSR propagation, unroll-8, norm-free (unchanged from round 3)
template <int W, int GS, bool RELU, bool BIAS, bool OUTSCALE>
__global__ __launch_bounds__(256) void k_prop3(const float* __restrict__ g,
                                               const float* __restrict__ addv, int astride,
                                               const float* __restrict__ bias,
                                               const float* __restrict__ dinv,
                                               const int* __restrict__ csr_src,
                                               const int* __restrict__ row_ptr,
                                               float* __restrict__ out, int ostride, int n) {
  const int lane = threadIdx.x & 63;
  const int node = (blockIdx.x * blockDim.x + threadIdx.x) >> 6;
  if (node >= n) return;
  const int beg = row_ptr[node];
  const int end = row_ptr[node + 1];
  const float dv = dinv[node];
  if (W == 64 || lane < W) {
    const float* gl = g + lane;
    float a0 = 0.f, a1 = 0.f, a2 = 0.f, a3 = 0.f, a4 = 0.f, a5 = 0.f, a6 = 0.f, a7 = 0.f;
    int j = beg;
    for (; j + 7 < end; j += 8) {
      int s0 = csr_src[j], s1 = csr_src[j + 1], s2 = csr_src[j + 2], s3 = csr_src[j + 3];
      int s4 = csr_src[j + 4], s5 = csr_src[j + 5], s6 = csr_src[j + 6], s7 = csr_src[j + 7];
      a0 += gl[(size_t)s0 * GS];
      a1 += gl[(size_t)s1 * GS];
      a2 += gl[(size_t)s2 * GS];
      a3 += gl[(size_t)s3 * GS];
      a4 += gl[(size_t)s4 * GS];
      a5 += gl[(size_t)s5 * GS];
      a6 += gl[(size_t)s6 * GS];
      a7 += gl[(size_t)s7 * GS];
    }
    for (; j < end; ++j) a0 += gl[(size_t)csr_src[j] * GS];
    float G = ((a0 + a1) + (a2 + a3)) + ((a4 + a5) + (a6 + a7));
    float v = addv[(size_t)node * astride + lane] - dv * G;
    if (BIAS) v += bias[lane];
    if (OUTSCALE) v *= dv;
    if (RELU) v = fmaxf(v, 0.f);
    out[(size_t)node * ostride + lane] = v;
  }
}

extern "C" void kernel_launch(void* const* d_in, const int* in_sizes, int n_in,
                              void* d_out, int out_size, void* d_ws, size_t ws_size,
                              hipStream_t stream) {
  const float* x  = (const float*)d_in[0];
  const int*   ei = (const int*)d_in[1];
  const float* W1 = (const float*)d_in[2];
  const float* b1 = (const float*)d_in[3];
  const float* W2 = (const float*)d_in[4];
  const float* b2 = (const float*)d_in[5];
  float* out = (float*)d_out;

  const int N = in_sizes[0] / 128;
  const int E = in_sizes[1] / 2;
  const int* src = ei;
  const int* dst = ei + E;

  const int nbuk = (N + 127) >> 7;
  if (nbuk > MAXBUK) return;
  const int cpb = (E + NBLK_PART - 1) / NBLK_PART;

  char* p = (char*)d_ws;
  size_t used = 0;
  auto alloc = [&](size_t bytes) -> void* {
    void* r = p + used;
    used += (bytes + 255) & ~(size_t)255;
    return r;
  };
  unsigned int* degpk = (unsigned int*)alloc((size_t)((N + 3) / 4) * 4);
  float* dinv    = (float*)alloc((size_t)N * 4);
  int*   row_ptr = (int*)alloc((size_t)(N + 1) * 4);
  int*   csr_src = (int*)alloc((size_t)E * 4);
  int*   buktot  = (int*)alloc((size_t)MAXBUK * 4);
  unsigned short* Wfrag1 = (unsigned short*)alloc((size_t)4 * 12 * 64 * 8 * 2);  // 49KB
  unsigned short* Wfrag2 = (unsigned short*)alloc((size_t)2 * 8 * 64 * 8 * 2);   // 16KB
  float* regA = (float*)alloc((size_t)N * 192 * 4);  // Y; later Z2s; radix temps early
  float* regB = (float*)alloc((size_t)N * 128 * 4);  // Zs; later U
  if (used > ws_size) return;

  // radix temporaries alias regA (dead until gemm1 writes Y)
  unsigned int* packed = (unsigned int*)regA;  // E*4 = 6.4 MB
  int* histG = (int*)((char*)regA + (((size_t)E * 4 + 4096 + 255) & ~(size_t)255));

  float* Y   = regA;  // [N,192] = [Y0 | Y1->h | Ys2]
  float* Zs  = regB;  // [N,64]
  float* U   = regB;  // [N,128] = [U0 | U1 | Us2 | pad]
  float* Z2s = regA;  // [N,40]

  hipMemsetAsync(degpk, 0, (size_t)((N + 3) / 4) * 4, stream);

  k_passA<<<NBLK_PART, 256, 0, stream>>>(src, dst, E, cpb, degpk, histG, nbuk);
  k_dinv<<<(N + 255) / 256, 256, 0, stream>>>(degpk, dinv, N);
  k_scanA<<<nbuk, 256, 0, stream>>>(histG, buktot);
  k_scanB<<<1, 256, 0, stream>>>(buktot, nbuk);
  k_passB<<<NBLK_PART, 256, 0, stream>>>(src, dst, E, cpb, histG, buktot, nbuk, packed);
  k_passC<<<nbuk, 256, 0, stream>>>(packed, buktot, nbuk, E, N, csr_src, row_ptr);

  k_wfrag<<<(4 * 12 * 64 + 255) / 256, 256, 0, stream>>>(W1, Wfrag1, 128, 64, 12);
  k_wfrag<<<(2 * 8 * 64 + 255) / 256, 256, 0, stream>>>(W2, Wfrag2, 64, 40, 8);

  const int pb = ((size_t)N * 64 + 255) / 256;
  const int gb = (N + 63) / 64;

  // layer 1: Y = bf16(x)@[We0|We1|We2] (cols 128-191 dinv-scaled);
  //          Zs = dinv*(Y1 - dinv*G(Ys2)); h = relu(Y0 - dinv*G(Zs) + b1) -> Y cols 64-127
  k_gemm_mfma<128, 12, 128, 128, 192, 192><<<gb, 256, 0, stream>>>(x, Wfrag1, dinv, Y, N);
  k_prop3<64, 192, false, false, true><<<pb, 256, 0, stream>>>(
      Y + 128, Y + 64, 192, nullptr, dinv, csr_src, row_ptr, Zs, 64, N);
  k_prop3<64, 64, true, true, false><<<pb, 256, 0, stream>>>(
      Zs, Y, 192, b1, dinv, csr_src, row_ptr, Y + 64, 192, N);
  // layer 2: U = bf16(h)@[Ve0|Ve1|Ve2|0] (cols 80-119 dinv-scaled);
  //          Z2s = dinv*(U1 - dinv*G(Us2)); out = U0 - dinv*G(Z2s) + b2
  k_gemm_mfma<64, 8, 192, 80, 120, 128><<<gb, 256, 0, stream>>>(Y + 64, Wfrag2, dinv, U, N);
  k_prop3<40, 128, false, false, true><<<pb, 256, 0, stream>>>(
      U + 80, U + 40, 128, nullptr, dinv, csr_src, row_ptr, Z2s, 40, N);
  k_prop3<40, 40, false, true, false><<<pb, 256, 0, stream>>>(
      Z2s, U, 128, b2, dinv, csr_src, row_ptr, out, 40, N);
}

// Round 5
// 412.323 us; speedup vs baseline: 1.9503x; 1.1777x over previous
//
#include <hip/hip_runtime.h>

// ChebConv x2: N=100000, E=1600000, K=3, IN=128, HID=64, OUT=40
// Round 5:
//  - CSR build with ZERO global atomics: passA = dual LDS histograms
//    (dst-buckets + src-buckets); passB scatters packed dst-edges AND
//    src-bucket bytes; passC = CSR finalize; passC2 = deg/dinv from bytes.
//  - all prop gather sources stored as bf16 (half gather bytes); k=0 residual
//    paths stay fp32. gemm epilogues emit split fp32/bf16 outputs directly.
//  - MFMA bf16 GEMMs (16x16x32) with pre-swizzled W fragments (round 4).

#define NBLK_PART 1024
#define MAXBUK 1024

typedef __attribute__((ext_vector_type(8))) short bf16x8;
typedef __attribute__((ext_vector_type(4))) float f32x4;

__device__ inline unsigned short f2bf(float f) {
  unsigned u = __float_as_uint(f);
  return (unsigned short)((u + 0x7FFFu + ((u >> 16) & 1u)) >> 16);
}
__device__ inline unsigned pk2(float a, float b) {
  return (unsigned)f2bf(a) | ((unsigned)f2bf(b) << 16);
}
__device__ inline float bf2f(unsigned short us) {
  return __uint_as_float((unsigned)us << 16);
}

// pass A: per-block LDS histograms of dst>>7 and src>>7 (no global atomics)
__global__ __launch_bounds__(256) void k_passA(const int* __restrict__ src,
                                               const int* __restrict__ dst, int E, int cpb,
                                               int* __restrict__ histGd,
                                               int* __restrict__ histGs, int nbuk) {
  __shared__ int histD[MAXBUK], histS[MAXBUK];
  const int t = threadIdx.x, b = blockIdx.x;
  for (int k = t; k < nbuk; k += 256) {
    histD[k] = 0;
    histS[k] = 0;
  }
  __syncthreads();
  const int e0 = b * cpb;
  const int e1 = min(E, e0 + cpb);
  for (int e = e0 + t; e < e1; e += 256) {
    atomicAdd(&histD[dst[e] >> 7], 1);
    atomicAdd(&histS[src[e] >> 7], 1);
  }
  __syncthreads();
  for (int k = t; k < nbuk; k += 256) {
    histGd[k * NBLK_PART + b] = histD[k];
    histGs[k * NBLK_PART + b] = histS[k];
  }
}

// per bucket: exclusive scan over the 1024 partition blocks; grid = 2*nbuk
__global__ __launch_bounds__(256) void k_scanA(int* __restrict__ histGd,
                                               int* __restrict__ histGs,
                                               int* __restrict__ buktotD,
                                               int* __restrict__ buktotS, int nbuk) {
  __shared__ int sh[256];
  const int bb = blockIdx.x, t = threadIdx.x;
  int* hist = (bb < nbuk) ? histGd : histGs;
  int* tot = (bb < nbuk) ? buktotD : buktotS;
  const int b = (bb < nbuk) ? bb : bb - nbuk;
  const int base = b * NBLK_PART;
  int v[4];
  int s = 0;
#pragma unroll
  for (int i = 0; i < 4; i++) {
    v[i] = hist[base + t * 4 + i];
    s += v[i];
  }
  int run = s;
  sh[t] = run;
  __syncthreads();
  for (int off = 1; off < 256; off <<= 1) {
    int x = (t >= off) ? sh[t - off] : 0;
    __syncthreads();
    run += x;
    sh[t] = run;
    __syncthreads();
  }
  if (t == 255) tot[b] = run;
  int p = run - s;
#pragma unroll
  for (int i = 0; i < 4; i++) {
    hist[base + t * 4 + i] = p;
    p += v[i];
  }
}

// exclusive scan in place of two arrays (grid=2), nb <= 1024
__global__ __launch_bounds__(256) void k_scanB(int* __restrict__ aD, int* __restrict__ aS,
                                               int nb) {
  __shared__ int sh[256];
  int* a = (blockIdx.x == 0) ? aD : aS;
  const int t = threadIdx.x;
  int v[4];
  int s = 0;
#pragma unroll
  for (int i = 0; i < 4; i++) {
    int idx = t * 4 + i;
    v[i] = (idx < nb) ? a[idx] : 0;
    s += v[i];
  }
  int run = s;
  sh[t] = run;
  __syncthreads();
  for (int off = 1; off < 256; off <<= 1) {
    int x = (t >= off) ? sh[t - off] : 0;
    __syncthreads();
    run += x;
    sh[t] = run;
    __syncthreads();
  }
  int p = run - s;
#pragma unroll
  for (int i = 0; i < 4; i++) {
    int idx = t * 4 + i;
    if (idx < nb) a[idx] = p;
    p += v[i];
  }
}

// pass B: scatter (src<<7)|(dst&127) into dst-bucket order AND (src&127)
// bytes into src-bucket order, LDS cursors only
__global__ __launch_bounds__(256) void k_passB(const int* __restrict__ src,
                                               const int* __restrict__ dst, int E, int cpb,
                                               const int* __restrict__ histGd,
                                               const int* __restrict__ histGs,
                                               const int* __restrict__ bukoffD,
                                               const int* __restrict__ bukoffS, int nbuk,
                                               unsigned int* __restrict__ packed,
                                               unsigned char* __restrict__ pksrc) {
  __shared__ int curD[MAXBUK], curS[MAXBUK];
  const int t = threadIdx.x, b = blockIdx.x;
  for (int k = t; k < nbuk; k += 256) {
    curD[k] = bukoffD[k] + histGd[k * NBLK_PART + b];
    curS[k] = bukoffS[k] + histGs[k * NBLK_PART + b];
  }
  __syncthreads();
  const int e0 = b * cpb;
  const int e1 = min(E, e0 + cpb);
  for (int e = e0 + t; e < e1; e += 256) {
    int s = src[e], d = dst[e];
    int slot = atomicAdd(&curD[d >> 7], 1);
    packed[slot] = ((unsigned)s << 7) | (unsigned)(d & 127);
    int slot2 = atomicAdd(&curS[s >> 7], 1);
    pksrc[slot2] = (unsigned char)(s & 127);
  }
}

// pass C: per-bucket (128 nodes) CSR finalize fully in LDS
__global__ __launch_bounds__(256) void k_passC(const unsigned int* __restrict__ packed,
                                               const int* __restrict__ bukoff, int nbuk,
                                               int E, int n, int* __restrict__ csr_src,
                                               int* __restrict__ row_ptr) {
  __shared__ int cnt[128], scn[128], cur[128];
  const int t = threadIdx.x, b = blockIdx.x;
  if (t < 128) cnt[t] = 0;
  __syncthreads();
  const int e0 = bukoff[b];
  const int e1 = (b + 1 < nbuk) ? bukoff[b + 1] : E;
  for (int e = e0 + t; e < e1; e += 256) atomicAdd(&cnt[packed[e] & 127], 1);
  __syncthreads();
  if (t < 128) scn[t] = cnt[t];
  __syncthreads();
  for (int off = 1; off < 128; off <<= 1) {
    int x = (t < 128 && t >= off) ? scn[t - off] : 0;
    __syncthreads();
    if (t < 128) scn[t] += x;
    __syncthreads();
  }
  if (t < 128) {
    int start = e0 + scn[t] - cnt[t];
    cur[t] = start;
    int node = (b << 7) + t;
    if (node < n) row_ptr[node] = start;
  }
  if (b == 0 && t == 0) row_ptr[n] = E;
  __syncthreads();
  for (int e = e0 + t; e < e1; e += 256) {
    unsigned v = packed[e];
    int slot = atomicAdd(&cur[v & 127], 1);
    csr_src[slot] = (int)(v >> 7);
  }
}

// pass C2: per src-bucket degree count from bytes -> dinv
__global__ __launch_bounds__(256) void k_passC2(const unsigned char* __restrict__ pksrc,
                                                const int* __restrict__ bukoff, int nbuk,
                                                int E, int n, float* __restrict__ dinv) {
  __shared__ int cnt[128];
  const int t = threadIdx.x, b = blockIdx.x;
  if (t < 128) cnt[t] = 0;
  __syncthreads();
  const int e0 = bukoff[b];
  const int e1 = (b + 1 < nbuk) ? bukoff[b + 1] : E;
  for (int e = e0 + t; e < e1; e += 256) atomicAdd(&cnt[pksrc[e]], 1);
  __syncthreads();
  if (t < 128) {
    int node = (b << 7) + t;
    if (node < n) {
      int d = cnt[t];
      dinv[node] = (d > 0) ? rsqrtf((float)d) : 0.f;
    }
  }
}

// pre-swizzle effective weights into MFMA B-fragment order, bf16
__global__ void k_wfrag(const float* __restrict__ W, unsigned short* __restrict__ Wfrag,
                        int INF, int OUTC, int NT) {
  int idx = blockIdx.x * 256 + threadIdx.x;
  int total = (INF / 32) * NT * 64;
  if (idx >= total) return;
  int lane = idx & 63;
  int nt = (idx >> 6) % NT;
  int ks = idx / (64 * NT);
  int col = nt * 16 + (lane & 15);
  int kb = ks * 32 + (lane >> 4) * 8;
  unsigned short o8[8];
#pragma unroll
  for (int j = 0; j < 8; j++) {
    int k = kb + j;
    float v = 0.f;
    if (col < 3 * OUTC) {
      int m = col / OUTC, o = col - m * OUTC;
    if (m == 0)      v = W[(0 * INF + k) * OUTC + o] - W[(2 * INF + k) * OUTC + o];
      else if (m == 1) v = W[(1 * INF + k) * OUTC + o];
      else             v = 2.f * W[(2 * INF + k) * OUTC + o];
    }
    o8[j] = f2bf(v);
  }
  uint4 r;
  r.x = (unsigned)o8[0] | ((unsigned)o8[1] << 16);
  r.y = (unsigned)o8[2] | ((unsigned)o8[3] << 16);
  r.z = (unsigned)o8[4] | ((unsigned)o8[5] << 16);
  r.w = (unsigned)o8[6] | ((unsigned)o8[7] << 16);
  *reinterpret_cast<uint4*>(Wfrag + (size_t)idx * 8) = r;
}

// MFMA GEMM with split epilogue:
//   cols [0,C1)  -> Of0 fp32 stride S0
//   cols [C1,C2) -> Of1 fp32 stride S1
//   cols [C2,C3) -> Ob2 bf16 stride S2, scaled by dinv[row]
template <int INF, int NT, bool XBF16, int XSTR, int C1, int C2, int C3, int S0, int S1,
          int S2>
__global__ __launch_bounds__(256) void k_gemm_mfma(const void* __restrict__ Xv,
                                                   const unsigned short* __restrict__ Wfrag,
                                                   const float* __restrict__ dinv,
                                                   float* __restrict__ Of0,
                                                   float* __restrict__ Of1,
                                                   unsigned short* __restrict__ Ob2, int n) {
  constexpr int KSTEPS = INF / 32;
  constexpr int KP = INF + 8;
  __shared__ unsigned short XA[64 * KP];
  const int tid = threadIdx.x;
  const int lane = tid & 63;
  const int w = tid >> 6;
  const int n0 = blockIdx.x * 64;
  // stage X -> bf16 LDS
  {
    const int node = tid >> 2;
    const int k0 = (tid & 3) * (INF / 4);
    const bool ok = (n0 + node) < n;
    unsigned short* dp = &XA[node * KP + k0];
    if (XBF16) {
      const unsigned short* sp = (const unsigned short*)Xv + (size_t)(n0 + node) * XSTR + k0;
#pragma unroll
      for (int i = 0; i < INF / 32; i++) {
        uint4 u = make_uint4(0, 0, 0, 0);
        if (ok) u = *reinterpret_cast<const uint4*>(sp + 8 * i);
        *reinterpret_cast<uint4*>(dp + 8 * i) = u;
      }
    } else {
      const float* sp = (const float*)Xv + (size_t)(n0 + node) * XSTR + k0;
#pragma unroll
      for (int i = 0; i < INF / 32; i++) {
        float4 va = make_float4(0.f, 0.f, 0.f, 0.f), vb = va;
        if (ok) {
          va = *reinterpret_cast<const float4*>(sp + 8 * i);
          vb = *reinterpret_cast<const float4*>(sp + 8 * i + 4);
        }
        uint4 u;
        u.x = pk2(va.x, va.y);
        u.y = pk2(va.z, va.w);
        u.z = pk2(vb.x, vb.y);
        u.w = pk2(vb.z, vb.w);
        *reinterpret_cast<uint4*>(dp + 8 * i) = u;
      }
    }
  }
  __syncthreads();
  bf16x8 afrag[KSTEPS];
  {
    const unsigned short* arow = &XA[(16 * w + (lane & 15)) * KP + (lane >> 4) * 8];
#pragma unroll
    for (int ks = 0; ks < KSTEPS; ks++)
      afrag[ks] = *reinterpret_cast<const bf16x8*>(arow + ks * 32);
  }
  f32x4 acc[NT];
#pragma unroll
  for (int nt = 0; nt < NT; nt++) acc[nt] = (f32x4){0.f, 0.f, 0.f, 0.f};
  const unsigned short* wf = Wfrag + (size_t)lane * 8;
#pragma unroll
  for (int ks = 0; ks < KSTEPS; ks++) {
#pragma unroll
    for (int nt = 0; nt < NT; nt++) {
      bf16x8 b = *reinterpret_cast<const bf16x8*>(wf + (size_t)(ks * NT + nt) * 512);
      acc[nt] = __builtin_amdgcn_mfma_f32_16x16x32_bf16(afrag[ks], b, acc[nt], 0, 0, 0);
    }
  }
  const int rq = (lane >> 4) * 4;
#pragma unroll
  for (int r = 0; r < 4; r++) {
    int row = n0 + 16 * w + rq + r;
    if (row < n) {
      float dv = dinv[row];
#pragma unroll
      for (int nt = 0; nt < NT; nt++) {
        int col = nt * 16 + (lane & 15);
        float v = acc[nt][r];
        if (col < C1) {
          Of0[(size_t)row * S0 + col] = v;
        } else if (col < C2) {
          Of1[(size_t)row * S1 + (col - C1)] = v;
        } else if (col < C3) {
          Ob2[(size_t)row * S2 + (col - C2)] = f2bf(v * dv);
        }
      }
    }
  }
}

// wave-per-node CSR propagation, unroll-8; gather source is bf16,
// addv fp32; output bf16 or fp32
//   G = sum_j g[src[j]]; v = addv - dinv[d]*G (+bias) (*dinv) (relu)
template <int W, int GS, int AS, int OS, bool RELU, bool BIAS, bool OUTSCALE, bool OBF16>
__global__ __launch_bounds__(256) void k_prop5(const unsigned short* __restrict__ g,
                                               const float* __restrict__ addv,
                                               const float* __restrict__ bias,
                                               const float* __restrict__ dinv,
                                               const int* __restrict__ csr_src,
                                               const int* __restrict__ row_ptr,
                                               void* __restrict__ outv, int n) {
  const int lane = threadIdx.x & 63;
  const int node = (blockIdx.x * blockDim.x + threadIdx.x) >> 6;
  if (node >= n) return;
  const int beg = row_ptr[node];
  const int end = row_ptr[node + 1];
  const float dv = dinv[node];
  if (W == 64 || lane < W) {
    const unsigned short* gl = g + lane;
    float a0 = 0.f, a1 = 0.f, a2 = 0.f, a3 = 0.f, a4 = 0.f, a5 = 0.f, a6 = 0.f, a7 = 0.f;
    int j = beg;
    for (; j + 7 < end; j += 8) {
      int s0 = csr_src[j], s1 = csr_src[j + 1], s2 = csr_src[j + 2], s3 = csr_src[j + 3];
      int s4 = csr_src[j + 4], s5 = csr_src[j + 5], s6 = csr_src[j + 6], s7 = csr_src[j + 7];
      a0 += bf2f(gl[(size_t)s0 * GS]);
      a1 += bf2f(gl[(size_t)s1 * GS]);
      a2 += bf2f(gl[(size_t)s2 * GS]);
      a3 += bf2f(gl[(size_t)s3 * GS]);
      a4 += bf2f(gl[(size_t)s4 * GS]);
      a5 += bf2f(gl[(size_t)s5 * GS]);
      a6 += bf2f(gl[(size_t)s6 * GS]);
      a7 += bf2f(gl[(size_t)s7 * GS]);
    }
    for (; j < end; ++j) a0 += bf2f(gl[(size_t)csr_src[j] * GS]);
    float G = ((a0 + a1) + (a2 + a3)) + ((a4 + a5) + (a6 + a7));
    float v = addv[(size_t)node * AS + lane] - dv * G;
    if (BIAS) v += bias[lane];
    if (OUTSCALE) v *= dv;
    if (RELU) v = fmaxf(v, 0.f);
    if (OBF16)
      ((unsigned short*)outv)[(size_t)node * OS + lane] = f2bf(v);
    else
      ((float*)outv)[(size_t)node * OS + lane] = v;
  }
}

extern "C" void kernel_launch(void* const* d_in, const int* in_sizes, int n_in,
                              void* d_out, int out_size, void* d_ws, size_t ws_size,
                              hipStream_t stream) {
  const float* x  = (const float*)d_in[0];
  const int*   ei = (const int*)d_in[1];
  const float* W1 = (const float*)d_in[2];
  const float* b1 = (const float*)d_in[3];
  const float* W2 = (const float*)d_in[4];
  const float* b2 = (const float*)d_in[5];
  float* out = (float*)d_out;

  const int N = in_sizes[0] / 128;
  const int E = in_sizes[1] / 2;
  const int* src = ei;
  const int* dst = ei + E;

  const int nbuk = (N + 127) >> 7;
  if (nbuk > MAXBUK) return;
  const int cpb = (E + NBLK_PART - 1) / NBLK_PART;

  char* p = (char*)d_ws;
  size_t used = 0;
  auto alloc = [&](size_t bytes) -> void* {
    void* r = p + used;
    used += (bytes + 255) & ~(size_t)255;
    return r;
  };
  float* dinv    = (float*)alloc((size_t)N * 4);
  int*   row_ptr = (int*)alloc((size_t)(N + 1) * 4);
  int*   csr_src = (int*)alloc((size_t)E * 4);
  int*   buktotD = (int*)alloc((size_t)MAXBUK * 4);
  int*   buktotS = (int*)alloc((size_t)MAXBUK * 4);
  unsigned short* Wfrag1 = (unsigned short*)alloc((size_t)4 * 12 * 64 * 8 * 2);
  unsigned short* Wfrag2 = (unsigned short*)alloc((size_t)2 * 8 * 64 * 8 * 2);
  char* region = (char*)alloc((size_t)N * (64 * 4 * 2 + 64 * 2 * 2));  // 76.8 MB
  unsigned short* hb = (unsigned short*)alloc((size_t)N * 64 * 2);     // 12.8 MB
  if (used > ws_size) return;

  // layer-1 layout in region
  float* Y0f           = (float*)region;                               // [N,64] f32
  float* Y1f           = (float*)(region + (size_t)N * 64 * 4);        // [N,64] f32
  unsigned short* Ys2b = (unsigned short*)(region + (size_t)N * 64 * 8);       // [N,64] bf16
  unsigned short* Zsb  = (unsigned short*)(region + (size_t)N * 64 * 8 + (size_t)N * 64 * 2);
  // layer-2 layout aliases region (layer-1 dead by then)
  float* U0f           = (float*)region;                               // [N,40] f32
  float* U1f           = (float*)(region + (size_t)N * 40 * 4);        // [N,40] f32
  unsigned short* Us2b = (unsigned short*)(region + (size_t)N * 80 * 4);       // [N,64] bf16
  unsigned short* Z2sb = (unsigned short*)(region + (size_t)N * 80 * 4 + (size_t)N * 64 * 2);
  // radix temporaries alias region (dead before gemm1)
  unsigned int* packed = (unsigned int*)region;                        // E*4
  unsigned char* pksrc = (unsigned char*)(region + (size_t)E * 4);     // E*1
  int* histGd = (int*)(region + (size_t)E * 5 + 256);
  int* histGs = histGd + (size_t)MAXBUK * NBLK_PART;

  k_passA<<<NBLK_PART, 256, 0, stream>>>(src, dst, E, cpb, histGd, histGs, nbuk);
  k_scanA<<<2 * nbuk, 256, 0, stream>>>(histGd, histGs, buktotD, buktotS, nbuk);
  k_scanB<<<2, 256, 0, stream>>>(buktotD, buktotS, nbuk);
  k_passB<<<NBLK_PART, 256, 0, stream>>>(src, dst, E, cpb, histGd, histGs, buktotD, buktotS,
                                         nbuk, packed, pksrc);
  k_passC<<<nbuk, 256, 0, stream>>>(packed, buktotD, nbuk, E, N, csr_src, row_ptr);
  k_passC2<<<nbuk, 256, 0, stream>>>(pksrc, buktotS, nbuk, E, N, dinv);

  k_wfrag<<<(4 * 12 * 64 + 255) / 256, 256, 0, stream>>>(W1, Wfrag1, 128, 64, 12);
  k_wfrag<<<(2 * 8 * 64 + 255) / 256, 256, 0, stream>>>(W2, Wfrag2, 64, 40, 8);

  const int pb = ((size_t)N * 64 + 255) / 256;
  const int gb = (N + 63) / 64;

  // layer 1: [Y0|Y1|Ys2b] = bf16(x) @ Weff1 (Ys2 cols dinv-scaled, bf16)
  k_gemm_mfma<128, 12, false, 128, 64, 128, 192, 64, 64, 64>
      <<<gb, 256, 0, stream>>>(x, Wfrag1, dinv, Y0f, Y1f, Ys2b, N);
  // Zs = dinv*(Y1 - dinv*G(Ys2))  -> bf16
  k_prop5<64, 64, 64, 64, false, false, true, true><<<pb, 256, 0, stream>>>(
      Ys2b, Y1f, nullptr, dinv, csr_src, row_ptr, Zsb, N);
  // h = relu(Y0 - dinv*G(Zs) + b1) -> bf16
  k_prop5<64, 64, 64, 64, true, true, false, true><<<pb, 256, 0, stream>>>(
      Zsb, Y0f, b1, dinv, csr_src, row_ptr, hb, N);
  // layer 2: [U0|U1|Us2b] = h @ Weff2 (Us2 cols dinv-scaled, bf16)
  k_gemm_mfma<64, 8, true, 64, 40, 80, 120, 40, 40, 64>
      <<<gb, 256, 0, stream>>>(hb, Wfrag2, dinv, U0f, U1f, Us2b, N);
  // Z2s = dinv*(U1 - dinv*G(Us2)) -> bf16
  k_prop5<40, 64, 40, 64, false, false, true, true><<<pb, 256, 0, stream>>>(
      Us2b, U1f, nullptr, dinv, csr_src, row_ptr, Z2sb, N);
  // out = U0 - dinv*G(Z2s) + b2  (fp32)
  k_prop5<40, 64, 40, 40, false, true, false, false><<<pb, 256, 0, stream>>>(
      Z2sb, U0f, b2, dinv, csr_src, row_ptr, out, N);
}

// Round 6
// 411.912 us; speedup vs baseline: 1.9523x; 1.0010x over previous
//
#include <hip/hip_runtime.h>

// ChebConv x2: N=100000, E=1600000, K=3, IN=128, HID=64, OUT=40
// Round 5:
//  - CSR build with ZERO global atomics: passA = dual LDS histograms
//    (dst-buckets + src-buckets); passB scatters packed dst-edges AND
//    src-bucket bytes; passC = CSR finalize; passC2 = deg/dinv from bytes.
//  - all prop gather sources stored as bf16 (half gather bytes); k=0 residual
//    paths stay fp32. gemm epilogues emit split fp32/bf16 outputs directly.
//  - MFMA bf16 GEMMs (16x16x32) with pre-swizzled W fragments (round 4).

#define NBLK_PART 1024
#define MAXBUK 1024

typedef __attribute__((ext_vector_type(8))) short bf16x8;
typedef __attribute__((ext_vector_type(4))) float f32x4;

__device__ inline unsigned short f2bf(float f) {
  unsigned u = __float_as_uint(f);
  return (unsigned short)((u + 0x7FFFu + ((u >> 16) & 1u)) >> 16);
}
__device__ inline unsigned pk2(float a, float b) {
  return (unsigned)f2bf(a) | ((unsigned)f2bf(b) << 16);
}
__device__ inline float bf2f(unsigned short us) {
  return __uint_as_float((unsigned)us << 16);
}

// pass A: per-block LDS histograms of dst>>7 and src>>7 (no global atomics)
__global__ __launch_bounds__(256) void k_passA(const int* __restrict__ src,
                                               const int* __restrict__ dst, int E, int cpb,
                                               int* __restrict__ histGd,
                                               int* __restrict__ histGs, int nbuk) {
  __shared__ int histD[MAXBUK], histS[MAXBUK];
  const int t = threadIdx.x, b = blockIdx.x;
  for (int k = t; k < nbuk; k += 256) {
    histD[k] = 0;
    histS[k] = 0;
  }
  __syncthreads();
  const int e0 = b * cpb;
  const int e1 = min(E, e0 + cpb);
  for (int e = e0 + t; e < e1; e += 256) {
    atomicAdd(&histD[dst[e] >> 7], 1);
    atomicAdd(&histS[src[e] >> 7], 1);
  }
  __syncthreads();
  for (int k = t; k < nbuk; k += 256) {
    histGd[k * NBLK_PART + b] = histD[k];
    histGs[k * NBLK_PART + b] = histS[k];
  }
}

// per bucket: exclusive scan over the 1024 partition blocks; grid = 2*nbuk
__global__ __launch_bounds__(256) void k_scanA(int* __restrict__ histGd,
                                               int* __restrict__ histGs,
                                               int* __restrict__ buktotD,
                                               int* __restrict__ buktotS, int nbuk) {
  __shared__ int sh[256];
  const int bb = blockIdx.x, t = threadIdx.x;
  int* hist = (bb < nbuk) ? histGd : histGs;
  int* tot = (bb < nbuk) ? buktotD : buktotS;
  const int b = (bb < nbuk) ? bb : bb - nbuk;
  const int base = b * NBLK_PART;
  int v[4];
  int s = 0;
#pragma unroll
  for (int i = 0; i < 4; i++) {
    v[i] = hist[base + t * 4 + i];
    s += v[i];
  }
  int run = s;
  sh[t] = run;
  __syncthreads();
  for (int off = 1; off < 256; off <<= 1) {
    int x = (t >= off) ? sh[t - off] : 0;
    __syncthreads();
    run += x;
    sh[t] = run;
    __syncthreads();
  }
  if (t == 255) tot[b] = run;
  int p = run - s;
#pragma unroll
  for (int i = 0; i < 4; i++) {
    hist[base + t * 4 + i] = p;
    p += v[i];
  }
}

// exclusive scan in place of two arrays (grid=2), nb <= 1024
__global__ __launch_bounds__(256) void k_scanB(int* __restrict__ aD, int* __restrict__ aS,
                                               int nb) {
  __shared__ int sh[256];
  int* a = (blockIdx.x == 0) ? aD : aS;
  const int t = threadIdx.x;
  int v[4];
  int s = 0;
#pragma unroll
  for (int i = 0; i < 4; i++) {
    int idx = t * 4 + i;
    v[i] = (idx < nb) ? a[idx] : 0;
    s += v[i];
  }
  int run = s;
  sh[t] = run;
  __syncthreads();
  for (int off = 1; off < 256; off <<= 1) {
    int x = (t >= off) ? sh[t - off] : 0;
    __syncthreads();
    run += x;
    sh[t] = run;
    __syncthreads();
  }
  int p = run - s;
#pragma unroll
  for (int i = 0; i < 4; i++) {
    int idx = t * 4 + i;
    if (idx < nb) a[idx] = p;
    p += v[i];
  }
}

// pass B: scatter (src<<7)|(dst&127) into dst-bucket order AND (src&127)
// bytes into src-bucket order, LDS cursors only
__global__ __launch_bounds__(256) void k_passB(const int* __restrict__ src,
                                               const int* __restrict__ dst, int E, int cpb,
                                               const int* __restrict__ histGd,
                                               const int* __restrict__ histGs,
                                               const int* __restrict__ bukoffD,
                                               const int* __restrict__ bukoffS, int nbuk,
                                               unsigned int* __restrict__ packed,
                                               unsigned char* __restrict__ pksrc) {
  __shared__ int curD[MAXBUK], curS[MAXBUK];
  const int t = threadIdx.x, b = blockIdx.x;
  for (int k = t; k < nbuk; k += 256) {
    curD[k] = bukoffD[k] + histGd[k * NBLK_PART + b];
    curS[k] = bukoffS[k] + histGs[k * NBLK_PART + b];
  }
  __syncthreads();
  const int e0 = b * cpb;
  const int e1 = min(E, e0 + cpb);
  for (int e = e0 + t; e < e1; e += 256) {
    int s = src[e], d = dst[e];
    int slot = atomicAdd(&curD[d >> 7], 1);
    packed[slot] = ((unsigned)s << 7) | (unsigned)(d & 127);
    int slot2 = atomicAdd(&curS[s >> 7], 1);
    pksrc[slot2] = (unsigned char)(s & 127);
  }
}

// pass C: per-bucket (128 nodes) CSR finalize fully in LDS
__global__ __launch_bounds__(256) void k_passC(const unsigned int* __restrict__ packed,
                                               const int* __restrict__ bukoff, int nbuk,
                                               int E, int n, int* __restrict__ csr_src,
                                               int* __restrict__ row_ptr) {
  __shared__ int cnt[128], scn[128], cur[128];
  const int t = threadIdx.x, b = blockIdx.x;
  if (t < 128) cnt[t] = 0;
  __syncthreads();
  const int e0 = bukoff[b];
  const int e1 = (b + 1 < nbuk) ? bukoff[b + 1] : E;
  for (int e = e0 + t; e < e1; e += 256) atomicAdd(&cnt[packed[e] & 127], 1);
  __syncthreads();
  if (t < 128) scn[t] = cnt[t];
  __syncthreads();
  for (int off = 1; off < 128; off <<= 1) {
    int x = (t < 128 && t >= off) ? scn[t - off] : 0;
    __syncthreads();
    if (t < 128) scn[t] += x;
    __syncthreads();
  }
  if (t < 128) {
    int start = e0 + scn[t] - cnt[t];
    cur[t] = start;
    int node = (b << 7) + t;
    if (node < n) row_ptr[node] = start;
  }
  if (b == 0 && t == 0) row_ptr[n] = E;
  __syncthreads();
  for (int e = e0 + t; e < e1; e += 256) {
    unsigned v = packed[e];
    int slot = atomicAdd(&cur[v & 127], 1);
    csr_src[slot] = (int)(v >> 7);
  }
}

// pass C2: per src-bucket degree count from bytes -> dinv
__global__ __launch_bounds__(256) void k_passC2(const unsigned char* __restrict__ pksrc,
                                                const int* __restrict__ bukoff, int nbuk,
                                                int E, int n, float* __restrict__ dinv) {
  __shared__ int cnt[128];
  const int t = threadIdx.x, b = blockIdx.x;
  if (t < 128) cnt[t] = 0;
  __syncthreads();
  const int e0 = bukoff[b];
  const int e1 = (b + 1 < nbuk) ? bukoff[b + 1] : E;
  for (int e = e0 + t; e < e1; e += 256) atomicAdd(&cnt[pksrc[e]], 1);
  __syncthreads();
  if (t < 128) {
    int node = (b << 7) + t;
    if (node < n) {
      int d = cnt[t];
      dinv[node] = (d > 0) ? rsqrtf((float)d) : 0.f;
    }
  }
}

// pre-swizzle effective weights into MFMA B-fragment order, bf16
__global__ void k_wfrag(const float* __restrict__ W, unsigned short* __restrict__ Wfrag,
                        int INF, int OUTC, int NT) {
  int idx = blockIdx.x * 256 + threadIdx.x;
  int total = (INF / 32) * NT * 64;
  if (idx >= total) return;
  int lane = idx & 63;
  int nt = (idx >> 6) % NT;
  int ks = idx / (64 * NT);
  int col = nt * 16 + (lane & 15);
  int kb = ks * 32 + (lane >> 4) * 8;
  unsigned short o8[8];
#pragma unroll
  for (int j = 0; j < 8; j++) {
    int k = kb + j;
    float v = 0.f;
    if (col < 3 * OUTC) {
      int m = col / OUTC, o = col - m * OUTC;
    if (m == 0)      v = W[(0 * INF + k) * OUTC + o] - W[(2 * INF + k) * OUTC + o];
      else if (m == 1) v = W[(1 * INF + k) * OUTC + o];
      else             v = 2.f * W[(2 * INF + k) * OUTC + o];
    }
    o8[j] = f2bf(v);
  }
  uint4 r;
  r.x = (unsigned)o8[0] | ((unsigned)o8[1] << 16);
  r.y = (unsigned)o8[2] | ((unsigned)o8[3] << 16);
  r.z = (unsigned)o8[4] | ((unsigned)o8[5] << 16);
  r.w = (unsigned)o8[6] | ((unsigned)o8[7] << 16);
  *reinterpret_cast<uint4*>(Wfrag + (size_t)idx * 8) = r;
}

// MFMA GEMM with split epilogue:
//   cols [0,C1)  -> Of0 fp32 stride S0
//   cols [C1,C2) -> Of1 fp32 stride S1
//   cols [C2,C3) -> Ob2 bf16 stride S2, scaled by dinv[row]
template <int INF, int NT, bool XBF16, int XSTR, int C1, int C2, int C3, int S0, int S1,
          int S2>
__global__ __launch_bounds__(256) void k_gemm_mfma(const void* __restrict__ Xv,
                                                   const unsigned short* __restrict__ Wfrag,
                                                   const float* __restrict__ dinv,
                                                   float* __restrict__ Of0,
                                                   float* __restrict__ Of1,
                                                   unsigned short* __restrict__ Ob2, int n) {
  constexpr int KSTEPS = INF / 32;
  constexpr int KP = INF + 8;
  __shared__ unsigned short XA[64 * KP];
  const int tid = threadIdx.x;
  const int lane = tid & 63;
  const int w = tid >> 6;
  const int n0 = blockIdx.x * 64;
  // stage X -> bf16 LDS
  {
    const int node = tid >> 2;
    const int k0 = (tid & 3) * (INF / 4);
    const bool ok = (n0 + node) < n;
    unsigned short* dp = &XA[node * KP + k0];
    if (XBF16) {
      const unsigned short* sp = (const unsigned short*)Xv + (size_t)(n0 + node) * XSTR + k0;
#pragma unroll
      for (int i = 0; i < INF / 32; i++) {
        uint4 u = make_uint4(0, 0, 0, 0);
        if (ok) u = *reinterpret_cast<const uint4*>(sp + 8 * i);
        *reinterpret_cast<uint4*>(dp + 8 * i) = u;
      }
    } else {
      const float* sp = (const float*)Xv + (size_t)(n0 + node) * XSTR + k0;
#pragma unroll
      for (int i = 0; i < INF / 32; i++) {
        float4 va = make_float4(0.f, 0.f, 0.f, 0.f), vb = va;
        if (ok) {
          va = *reinterpret_cast<const float4*>(sp + 8 * i);
          vb = *reinterpret_cast<const float4*>(sp + 8 * i + 4);
        }
        uint4 u;
        u.x = pk2(va.x, va.y);
        u.y = pk2(va.z, va.w);
        u.z = pk2(vb.x, vb.y);
        u.w = pk2(vb.z, vb.w);
        *reinterpret_cast<uint4*>(dp + 8 * i) = u;
      }
    }
  }
  __syncthreads();
  bf16x8 afrag[KSTEPS];
  {
    const unsigned short* arow = &XA[(16 * w + (lane & 15)) * KP + (lane >> 4) * 8];
#pragma unroll
    for (int ks = 0; ks < KSTEPS; ks++)
      afrag[ks] = *reinterpret_cast<const bf16x8*>(arow + ks * 32);
  }
  f32x4 acc[NT];
#pragma unroll
  for (int nt = 0; nt < NT; nt++) acc[nt] = (f32x4){0.f, 0.f, 0.f, 0.f};
  const unsigned short* wf = Wfrag + (size_t)lane * 8;
#pragma unroll
  for (int ks = 0; ks < KSTEPS; ks++) {
#pragma unroll
    for (int nt = 0; nt < NT; nt++) {
      bf16x8 b = *reinterpret_cast<const bf16x8*>(wf + (size_t)(ks * NT + nt) * 512);
      acc[nt] = __builtin_amdgcn_mfma_f32_16x16x32_bf16(afrag[ks], b, acc[nt], 0, 0, 0);
    }
  }
  const int rq = (lane >> 4) * 4;
#pragma unroll
  for (int r = 0; r < 4; r++) {
    int row = n0 + 16 * w + rq + r;
    if (row < n) {
      float dv = dinv[row];
#pragma unroll
      for (int nt = 0; nt < NT; nt++) {
        int col = nt * 16 + (lane & 15);
        float v = acc[nt][r];
        if (col < C1) {
          Of0[(size_t)row * S0 + col] = v;
        } else if (col < C2) {
          Of1[(size_t)row * S1 + (col - C1)] = v;
        } else if (col < C3) {
          Ob2[(size_t)row * S2 + (col - C2)] = f2bf(v * dv);
        }
      }
    }
  }
}

// wave-per-node CSR propagation, unroll-8; gather source is bf16,
// addv fp32; output bf16 or fp32
//   G = sum_j g[src[j]]; v = addv - dinv[d]*G (+bias) (*dinv) (relu)
template <int W, int GS, int AS, int OS, bool RELU, bool BIAS, bool OUTSCALE, bool OBF16>
__global__ __launch_bounds__(256) void k_prop5(const unsigned short* __restrict__ g,
                                               const float* __restrict__ addv,
                                               const float* __restrict__ bias,
                                               const float* __restrict__ dinv,
                                               const int* __restrict__ csr_src,
                                               const int* __restrict__ row_ptr,
                                               void* __restrict__ outv, int n) {
  const int lane = threadIdx.x & 63;
  const int node = (blockIdx.x * blockDim.x + threadIdx.x) >> 6;
  if (node >= n) return;
  const int beg = row_ptr[node];
  const int end = row_ptr[node + 1];
  const float dv = dinv[node];
  if (W == 64 || lane < W) {
    const unsigned short* gl = g + lane;
    float a0 = 0.f, a1 = 0.f, a2 = 0.f, a3 = 0.f, a4 = 0.f, a5 = 0.f, a6 = 0.f, a7 = 0.f;
    int j = beg;
    for (; j + 7 < end; j += 8) {
      int s0 = csr_src[j], s1 = csr_src[j + 1], s2 = csr_src[j + 2], s3 = csr_src[j + 3];
      int s4 = csr_src[j + 4], s5 = csr_src[j + 5], s6 = csr_src[j + 6], s7 = csr_src[j + 7];
      a0 += bf2f(gl[(size_t)s0 * GS]);
      a1 += bf2f(gl[(size_t)s1 * GS]);
      a2 += bf2f(gl[(size_t)s2 * GS]);
      a3 += bf2f(gl[(size_t)s3 * GS]);
      a4 += bf2f(gl[(size_t)s4 * GS]);
      a5 += bf2f(gl[(size_t)s5 * GS]);
      a6 += bf2f(gl[(size_t)s6 * GS]);
      a7 += bf2f(gl[(size_t)s7 * GS]);
    }
    for (; j < end; ++j) a0 += bf2f(gl[(size_t)csr_src[j] * GS]);
    float G = ((a0 + a1) + (a2 + a3)) + ((a4 + a5) + (a6 + a7));
    float v = addv[(size_t)node * AS + lane] - dv * G;
    if (BIAS) v += bias[lane];
    if (OUTSCALE) v *= dv;
    if (RELU) v = fmaxf(v, 0.f);
    if (OBF16)
      ((unsigned short*)outv)[(size_t)node * OS + lane] = f2bf(v);
    else
      ((float*)outv)[(size_t)node * OS + lane] = v;
  }
}

extern "C" void kernel_launch(void* const* d_in, const int* in_sizes, int n_in,
                              void* d_out, int out_size, void* d_ws, size_t ws_size,
                              hipStream_t stream) {
  const float* x  = (const float*)d_in[0];
  const int*   ei = (const int*)d_in[1];
  const float* W1 = (const float*)d_in[2];
  const float* b1 = (const float*)d_in[3];
  const float* W2 = (const float*)d_in[4];
  const float* b2 = (const float*)d_in[5];
  float* out = (float*)d_out;

  const int N = in_sizes[0] / 128;
  const int E = in_sizes[1] / 2;
  const int* src = ei;
  const int* dst = ei + E;

  const int nbuk = (N + 127) >> 7;
  if (nbuk > MAXBUK) return;
  const int cpb = (E + NBLK_PART - 1) / NBLK_PART;

  char* p = (char*)d_ws;
  size_t used = 0;
  auto alloc = [&](size_t bytes) -> void* {
    void* r = p + used;
    used += (bytes + 255) & ~(size_t)255;
    return r;
  };
  float* dinv    = (float*)alloc((size_t)N * 4);
  int*   row_ptr = (int*)alloc((size_t)(N + 1) * 4);
  int*   csr_src = (int*)alloc((size_t)E * 4);
  int*   buktotD = (int*)alloc((size_t)MAXBUK * 4);
  int*   buktotS = (int*)alloc((size_t)MAXBUK * 4);
  unsigned short* Wfrag1 = (unsigned short*)alloc((size_t)4 * 12 * 64 * 8 * 2);
  unsigned short* Wfrag2 = (unsigned short*)alloc((size_t)2 * 8 * 64 * 8 * 2);
  char* region = (char*)alloc((size_t)N * (64 * 4 * 2 + 64 * 2 * 2));  // 76.8 MB
  unsigned short* hb = (unsigned short*)alloc((size_t)N * 64 * 2);     // 12.8 MB
  if (used > ws_size) return;

  // layer-1 layout in region
  float* Y0f           = (float*)region;                               // [N,64] f32
  float* Y1f           = (float*)(region + (size_t)N * 64 * 4);        // [N,64] f32
  unsigned short* Ys2b = (unsigned short*)(region + (size_t)N * 64 * 8);       // [N,64] bf16
  unsigned short* Zsb  = (unsigned short*)(region + (size_t)N * 64 * 8 + (size_t)N * 64 * 2);
  // layer-2 layout aliases region (layer-1 dead by then)
  float* U0f           = (float*)region;                               // [N,40] f32
  float* U1f           = (float*)(region + (size_t)N * 40 * 4);        // [N,40] f32
  unsigned short* Us2b = (unsigned short*)(region + (size_t)N * 80 * 4);       // [N,64] bf16
  unsigned short* Z2sb = (unsigned short*)(region + (size_t)N * 80 * 4 + (size_t)N * 64 * 2);
  // radix temporaries alias region (dead before gemm1)
  unsigned int* packed = (unsigned int*)region;                        // E*4
  unsigned char* pksrc = (unsigned char*)(region + (size_t)E * 4);     // E*1
  int* histGd = (int*)(region + (size_t)E * 5 + 256);
  int* histGs = histGd + (size_t)MAXBUK * NBLK_PART;

  k_passA<<<NBLK_PART, 256, 0, stream>>>(src, dst, E, cpb, histGd, histGs, nbuk);
  k_scanA<<<2 * nbuk, 256, 0, stream>>>(histGd, histGs, buktotD, buktotS, nbuk);
  k_scanB<<<2, 256, 0, stream>>>(buktotD, buktotS, nbuk);
  k_passB<<<NBLK_PART, 256, 0, stream>>>(src, dst, E, cpb, histGd, histGs, buktotD, buktotS,
                                         nbuk, packed, pksrc);
  k_passC<<<nbuk, 256, 0, stream>>>(packed, buktotD, nbuk, E, N, csr_src, row_ptr);
  k_passC2<<<nbuk, 256, 0, stream>>>(pksrc, buktotS, nbuk, E, N, dinv);

  k_wfrag<<<(4 * 12 * 64 + 255) / 256, 256, 0, stream>>>(W1, Wfrag1, 128, 64, 12);
  k_wfrag<<<(2 * 8 * 64 + 255) / 256, 256, 0, stream>>>(W2, Wfrag2, 64, 40, 8);

  const int pb = ((size_t)N * 64 + 255) / 256;
  const int gb = (N + 63) / 64;

  // layer 1: [Y0|Y1|Ys2b] = bf16(x) @ Weff1 (Ys2 cols dinv-scaled, bf16)
  k_gemm_mfma<128, 12, false, 128, 64, 128, 192, 64, 64, 64>
      <<<gb, 256, 0, stream>>>(x, Wfrag1, dinv, Y0f, Y1f, Ys2b, N);
  // Zs = dinv*(Y1 - dinv*G(Ys2))  -> bf16
  k_prop5<64, 64, 64, 64, false, false, true, true><<<pb, 256, 0, stream>>>(
      Ys2b, Y1f, nullptr, dinv, csr_src, row_ptr, Zsb, N);
  // h = relu(Y0 - dinv*G(Zs) + b1) -> bf16
  k_prop5<64, 64, 64, 64, true, true, false, true><<<pb, 256, 0, stream>>>(
      Zsb, Y0f, b1, dinv, csr_src, row_ptr, hb, N);
  // layer 2: [U0|U1|Us2b] = h @ Weff2 (Us2 cols dinv-scaled, bf16)
  k_gemm_mfma<64, 8, true, 64, 40, 80, 120, 40, 40, 64>
      <<<gb, 256, 0, stream>>>(hb, Wfrag2, dinv, U0f, U1f, Us2b, N);
  // Z2s = dinv*(U1 - dinv*G(Us2)) -> bf16
  k_prop5<40, 64, 40, 64, false, false, true, true><<<pb, 256, 0, stream>>>(
      Us2b, U1f, nullptr, dinv, csr_src, row_ptr, Z2sb, N);
  // out = U0 - dinv*G(Z2s) + b2  (fp32)
  k_prop5<40, 64, 40, 40, false, true, false, false><<<pb, 256, 0, stream>>>(
      Z2sb, U0f, b2, dinv, csr_src, row_ptr, out, N);
}

// Round 7
// 343.242 us; speedup vs baseline: 2.3428x; 1.2001x over previous
//
#include <hip/hip_runtime.h>

// ChebConv x2: N=100000, E=1600000, K=3, IN=128, HID=64, OUT=40
// Round 6:
//  - props restructured to multi-row vectorized gathers: 4 lane-groups x 16
//    lanes, each instruction fetches 4 rows (512B; 80B/row masked for F=40),
//    uint2 per lane, packed bf16 converts, shfl_xor(16/32) group reduce.
//  - csr_src stored pre-scaled to row byte offsets (s<<7) in passC.
//  - CSR build (zero global atomics), MFMA GEMMs, bf16 buffers: round 5.

#define NBLK_PART 1024
#define MAXBUK 1024

typedef __attribute__((ext_vector_type(8))) short bf16x8;
typedef __attribute__((ext_vector_type(4))) float f32x4;

__device__ inline unsigned short f2bf(float f) {
  unsigned u = __float_as_uint(f);
  return (unsigned short)((u + 0x7FFFu + ((u >> 16) & 1u)) >> 16);
}
__device__ inline unsigned pk2(float a, float b) {
  return (unsigned)f2bf(a) | ((unsigned)f2bf(b) << 16);
}
__device__ inline float bflo(unsigned u) { return __uint_as_float(u << 16); }
__device__ inline float bfhi(unsigned u) { return __uint_as_float(u & 0xffff0000u); }

// pass A: per-block LDS histograms of dst>>7 and src>>7 (no global atomics)
__global__ __launch_bounds__(256) void k_passA(const int* __restrict__ src,
                                               const int* __restrict__ dst, int E, int cpb,
                                               int* __restrict__ histGd,
                                               int* __restrict__ histGs, int nbuk) {
  __shared__ int histD[MAXBUK], histS[MAXBUK];
  const int t = threadIdx.x, b = blockIdx.x;
  for (int k = t; k < nbuk; k += 256) {
    histD[k] = 0;
    histS[k] = 0;
  }
  __syncthreads();
  const int e0 = b * cpb;
  const int e1 = min(E, e0 + cpb);
  for (int e = e0 + t; e < e1; e += 256) {
    atomicAdd(&histD[dst[e] >> 7], 1);
    atomicAdd(&histS[src[e] >> 7], 1);
  }
  __syncthreads();
  for (int k = t; k < nbuk; k += 256) {
    histGd[k * NBLK_PART + b] = histD[k];
    histGs[k * NBLK_PART + b] = histS[k];
  }
}

// per bucket: exclusive scan over the 1024 partition blocks; grid = 2*nbuk
__global__ __launch_bounds__(256) void k_scanA(int* __restrict__ histGd,
                                               int* __restrict__ histGs,
                                               int* __restrict__ buktotD,
                                               int* __restrict__ buktotS, int nbuk) {
  __shared__ int sh[256];
  const int bb = blockIdx.x, t = threadIdx.x;
  int* hist = (bb < nbuk) ? histGd : histGs;
  int* tot = (bb < nbuk) ? buktotD : buktotS;
  const int b = (bb < nbuk) ? bb : bb - nbuk;
  const int base = b * NBLK_PART;
  int v[4];
  int s = 0;
#pragma unroll
  for (int i = 0; i < 4; i++) {
    v[i] = hist[base + t * 4 + i];
    s += v[i];
  }
  int run = s;
  sh[t] = run;
  __syncthreads();
  for (int off = 1; off < 256; off <<= 1) {
    int x = (t >= off) ? sh[t - off] : 0;
    __syncthreads();
    run += x;
    sh[t] = run;
    __syncthreads();
  }
  if (t == 255) tot[b] = run;
  int p = run - s;
#pragma unroll
  for (int i = 0; i < 4; i++) {
    hist[base + t * 4 + i] = p;
    p += v[i];
  }
}

// exclusive scan in place of two arrays (grid=2), nb <= 1024
__global__ __launch_bounds__(256) void k_scanB(int* __restrict__ aD, int* __restrict__ aS,
                                               int nb) {
  __shared__ int sh[256];
  int* a = (blockIdx.x == 0) ? aD : aS;
  const int t = threadIdx.x;
  int v[4];
  int s = 0;
#pragma unroll
  for (int i = 0; i < 4; i++) {
    int idx = t * 4 + i;
    v[i] = (idx < nb) ? a[idx] : 0;
    s += v[i];
  }
  int run = s;
  sh[t] = run;
  __syncthreads();
  for (int off = 1; off < 256; off <<= 1) {
    int x = (t >= off) ? sh[t - off] : 0;
    __syncthreads();
    run += x;
    sh[t] = run;
    __syncthreads();
  }
  int p = run - s;
#pragma unroll
  for (int i = 0; i < 4; i++) {
    int idx = t * 4 + i;
    if (idx < nb) a[idx] = p;
    p += v[i];
  }
}

// pass B: scatter (src<<7)|(dst&127) into dst-bucket order AND (src&127)
// bytes into src-bucket order, LDS cursors only
__global__ __launch_bounds__(256) void k_passB(const int* __restrict__ src,
                                               const int* __restrict__ dst, int E, int cpb,
                                               const int* __restrict__ histGd,
                                               const int* __restrict__ histGs,
                                               const int* __restrict__ bukoffD,
                                               const int* __restrict__ bukoffS, int nbuk,
                                               unsigned int* __restrict__ packed,
                                               unsigned char* __restrict__ pksrc) {
  __shared__ int curD[MAXBUK], curS[MAXBUK];
  const int t = threadIdx.x, b = blockIdx.x;
  for (int k = t; k < nbuk; k += 256) {
    curD[k] = bukoffD[k] + histGd[k * NBLK_PART + b];
    curS[k] = bukoffS[k] + histGs[k * NBLK_PART + b];
  }
  __syncthreads();
  const int e0 = b * cpb;
  const int e1 = min(E, e0 + cpb);
  for (int e = e0 + t; e < e1; e += 256) {
    int s = src[e], d = dst[e];
    int slot = atomicAdd(&curD[d >> 7], 1);
    packed[slot] = ((unsigned)s << 7) | (unsigned)(d & 127);
    int slot2 = atomicAdd(&curS[s >> 7], 1);
    pksrc[slot2] = (unsigned char)(s & 127);
  }
}

// pass C: per-bucket (128 nodes) CSR finalize fully in LDS.
// csr_src stores PRE-SCALED row byte offsets (src*128) for the bf16 gathers.
__global__ __launch_bounds__(256) void k_passC(const unsigned int* __restrict__ packed,
                                               const int* __restrict__ bukoff, int nbuk,
                                               int E, int n, int* __restrict__ csr_src,
                                               int* __restrict__ row_ptr) {
  __shared__ int cnt[128], scn[128], cur[128];
  const int t = threadIdx.x, b = blockIdx.x;
  if (t < 128) cnt[t] = 0;
  __syncthreads();
  const int e0 = bukoff[b];
  const int e1 = (b + 1 < nbuk) ? bukoff[b + 1] : E;
  for (int e = e0 + t; e < e1; e += 256) atomicAdd(&cnt[packed[e] & 127], 1);
  __syncthreads();
  if (t < 128) scn[t] = cnt[t];
  __syncthreads();
  for (int off = 1; off < 128; off <<= 1) {
    int x = (t < 128 && t >= off) ? scn[t - off] : 0;
    __syncthreads();
    if (t < 128) scn[t] += x;
    __syncthreads();
  }
  if (t < 128) {
    int start = e0 + scn[t] - cnt[t];
    cur[t] = start;
    int node = (b << 7) + t;
    if (node < n) row_ptr[node] = start;
  }
  if (b == 0 && t == 0) row_ptr[n] = E;
  __syncthreads();
  for (int e = e0 + t; e < e1; e += 256) {
    unsigned v = packed[e];
    int slot = atomicAdd(&cur[v & 127], 1);
    csr_src[slot] = (int)(v & ~127u);  // src*128 = byte offset of bf16[64] row
  }
}

// pass C2: per src-bucket degree count from bytes -> dinv
__global__ __launch_bounds__(256) void k_passC2(const unsigned char* __restrict__ pksrc,
                                                const int* __restrict__ bukoff, int nbuk,
                                                int E, int n, float* __restrict__ dinv) {
  __shared__ int cnt[128];
  const int t = threadIdx.x, b = blockIdx.x;
  if (t < 128) cnt[t] = 0;
  __syncthreads();
  const int e0 = bukoff[b];
  const int e1 = (b + 1 < nbuk) ? bukoff[b + 1] : E;
  for (int e = e0 + t; e < e1; e += 256) atomicAdd(&cnt[pksrc[e]], 1);
  __syncthreads();
  if (t < 128) {
    int node = (b << 7) + t;
    if (node < n) {
      int d = cnt[t];
      dinv[node] = (d > 0) ? rsqrtf((float)d) : 0.f;
    }
  }
}

// pre-swizzle effective weights into MFMA B-fragment order, bf16
__global__ void k_wfrag(const float* __restrict__ W, unsigned short* __restrict__ Wfrag,
                        int INF, int OUTC, int NT) {
  int idx = blockIdx.x * 256 + threadIdx.x;
  int total = (INF / 32) * NT * 64;
  if (idx >= total) return;
  int lane = idx & 63;
  int nt = (idx >> 6) % NT;
  int ks = idx / (64 * NT);
  int col = nt * 16 + (lane & 15);
  int kb = ks * 32 + (lane >> 4) * 8;
  unsigned short o8[8];
#pragma unroll
  for (int j = 0; j < 8; j++) {
    int k = kb + j;
    float v = 0.f;
    if (col < 3 * OUTC) {
      int m = col / OUTC, o = col - m * OUTC;
      if (m == 0)      v = W[(0 * INF + k) * OUTC + o] - W[(2 * INF + k) * OUTC + o];
      else if (m == 1) v = W[(1 * INF + k) * OUTC + o];
      else             v = 2.f * W[(2 * INF + k) * OUTC + o];
    }
    o8[j] = f2bf(v);
  }
  uint4 r;
  r.x = (unsigned)o8[0] | ((unsigned)o8[1] << 16);
  r.y = (unsigned)o8[2] | ((unsigned)o8[3] << 16);
  r.z = (unsigned)o8[4] | ((unsigned)o8[5] << 16);
  r.w = (unsigned)o8[6] | ((unsigned)o8[7] << 16);
  *reinterpret_cast<uint4*>(Wfrag + (size_t)idx * 8) = r;
}

// MFMA GEMM with split epilogue:
//   cols [0,C1)  -> Of0 fp32 stride S0
//   cols [C1,C2) -> Of1 fp32 stride S1
//   cols [C2,C3) -> Ob2 bf16 stride S2, scaled by dinv[row]
template <int INF, int NT, bool XBF16, int XSTR, int C1, int C2, int C3, int S0, int S1,
          int S2>
__global__ __launch_bounds__(256) void k_gemm_mfma(const void* __restrict__ Xv,
                                                   const unsigned short* __restrict__ Wfrag,
                                                   const float* __restrict__ dinv,
                                                   float* __restrict__ Of0,
                                                   float* __restrict__ Of1,
                                                   unsigned short* __restrict__ Ob2, int n) {
  constexpr int KSTEPS = INF / 32;
  constexpr int KP = INF + 8;
  __shared__ unsigned short XA[64 * KP];
  const int tid = threadIdx.x;
  const int lane = tid & 63;
  const int w = tid >> 6;
  const int n0 = blockIdx.x * 64;
  // stage X -> bf16 LDS
  {
    const int node = tid >> 2;
    const int k0 = (tid & 3) * (INF / 4);
    const bool ok = (n0 + node) < n;
    unsigned short* dp = &XA[node * KP + k0];
    if (XBF16) {
      const unsigned short* sp = (const unsigned short*)Xv + (size_t)(n0 + node) * XSTR + k0;
#pragma unroll
      for (int i = 0; i < INF / 32; i++) {
        uint4 u = make_uint4(0, 0, 0, 0);
        if (ok) u = *reinterpret_cast<const uint4*>(sp + 8 * i);
        *reinterpret_cast<uint4*>(dp + 8 * i) = u;
      }
    } else {
      const float* sp = (const float*)Xv + (size_t)(n0 + node) * XSTR + k0;
#pragma unroll
      for (int i = 0; i < INF / 32; i++) {
        float4 va = make_float4(0.f, 0.f, 0.f, 0.f), vb = va;
        if (ok) {
          va = *reinterpret_cast<const float4*>(sp + 8 * i);
          vb = *reinterpret_cast<const float4*>(sp + 8 * i + 4);
        }
        uint4 u;
        u.x = pk2(va.x, va.y);
        u.y = pk2(va.z, va.w);
        u.z = pk2(vb.x, vb.y);
        u.w = pk2(vb.z, vb.w);
        *reinterpret_cast<uint4*>(dp + 8 * i) = u;
      }
    }
  }
  __syncthreads();
  bf16x8 afrag[KSTEPS];
  {
    const unsigned short* arow = &XA[(16 * w + (lane & 15)) * KP + (lane >> 4) * 8];
#pragma unroll
    for (int ks = 0; ks < KSTEPS; ks++)
      afrag[ks] = *reinterpret_cast<const bf16x8*>(arow + ks * 32);
  }
  f32x4 acc[NT];
#pragma unroll
  for (int nt = 0; nt < NT; nt++) acc[nt] = (f32x4){0.f, 0.f, 0.f, 0.f};
  const unsigned short* wf = Wfrag + (size_t)lane * 8;
#pragma unroll
  for (int ks = 0; ks < KSTEPS; ks++) {
#pragma unroll
    for (int nt = 0; nt < NT; nt++) {
      bf16x8 b = *reinterpret_cast<const bf16x8*>(wf + (size_t)(ks * NT + nt) * 512);
      acc[nt] = __builtin_amdgcn_mfma_f32_16x16x32_bf16(afrag[ks], b, acc[nt], 0, 0, 0);
    }
  }
  const int rq = (lane >> 4) * 4;
#pragma unroll
  for (int r = 0; r < 4; r++) {
    int row = n0 + 16 * w + rq + r;
    if (row < n) {
      float dv = dinv[row];
#pragma unroll
      for (int nt = 0; nt < NT; nt++) {
        int col = nt * 16 + (lane & 15);
        float v = acc[nt][r];
        if (col < C1) {
          Of0[(size_t)row * S0 + col] = v;
        } else if (col < C2) {
          Of1[(size_t)row * S1 + (col - C1)] = v;
        } else if (col < C3) {
          Ob2[(size_t)row * S2 + (col - C2)] = f2bf(v * dv);
        }
      }
    }
  }
}

// wave-per-node CSR propagation, multi-row vectorized gather:
// 4 lane-groups x 16 lanes; group g gathers the row of edge j+g (uint2 = 4
// bf16 cols per lane, 8B); csr_src holds pre-scaled row byte offsets.
// shfl_xor(16/32) reduce; epilogue by group 0.
//   G = sum_j g[src[j]]; v = addv - dinv[d]*G (+bias) (*dinv) (relu)
template <int F, int AS, int OS, bool RELU, bool BIAS, bool OUTSCALE, bool OBF16>
__global__ __launch_bounds__(256) void k_prop6(const unsigned short* __restrict__ g,
                                               const float* __restrict__ addv,
                                               const float* __restrict__ bias,
                                               const float* __restrict__ dinv,
                                               const int* __restrict__ csr_src,
                                               const int* __restrict__ row_ptr,
                                               void* __restrict__ outv, int n) {
  constexpr int SUBW = F / 4;  // active col-quads per row (16 or 10)
  const int lane = threadIdx.x & 63;
  const int node = (blockIdx.x * blockDim.x + threadIdx.x) >> 6;
  if (node >= n) return;
  const int grp = lane >> 4;
  const int sub = lane & 15;
  const int beg = row_ptr[node];
  const int end = row_ptr[node + 1];
  float a0 = 0.f, a1 = 0.f, a2 = 0.f, a3 = 0.f;
  float b0 = 0.f, b1 = 0.f, b2 = 0.f, b3 = 0.f;
  if (SUBW == 16 || sub < SUBW) {
    const char* gb = (const char*)g + sub * 8;
    int j = beg;
    for (; j + 8 <= end; j += 8) {
      int sA = csr_src[j + grp];
      int sB = csr_src[j + 4 + grp];
      uint2 dA = *reinterpret_cast<const uint2*>(gb + sA);
      uint2 dB = *reinterpret_cast<const uint2*>(gb + sB);
      a0 += bflo(dA.x); a1 += bfhi(dA.x); a2 += bflo(dA.y); a3 += bfhi(dA.y);
      b0 += bflo(dB.x); b1 += bfhi(dB.x); b2 += bflo(dB.y); b3 += bfhi(dB.y);
    }
    for (; j < end; j += 4) {
      int e = j + grp;
      int s = csr_src[min(e, end - 1)];
      uint2 d = *reinterpret_cast<const uint2*>(gb + s);
      if (e >= end) { d.x = 0u; d.y = 0u; }
      a0 += bflo(d.x); a1 += bfhi(d.x); a2 += bflo(d.y); a3 += bfhi(d.y);
    }
  }
  float r0 = a0 + b0, r1 = a1 + b1, r2 = a2 + b2, r3 = a3 + b3;
  r0 += __shfl_xor(r0, 16); r0 += __shfl_xor(r0, 32);
  r1 += __shfl_xor(r1, 16); r1 += __shfl_xor(r1, 32);
  r2 += __shfl_xor(r2, 16); r2 += __shfl_xor(r2, 32);
  r3 += __shfl_xor(r3, 16); r3 += __shfl_xor(r3, 32);
  if (grp == 0 && (SUBW == 16 || sub < SUBW)) {
    const float dv = dinv[node];
    float4 av = *reinterpret_cast<const float4*>(addv + (size_t)node * AS + sub * 4);
    float v0 = av.x - dv * r0;
    float v1 = av.y - dv * r1;
    float v2 = av.z - dv * r2;
    float v3 = av.w - dv * r3;
    if (BIAS) {
      float4 bv = *reinterpret_cast<const float4*>(bias + sub * 4);
      v0 += bv.x; v1 += bv.y; v2 += bv.z; v3 += bv.w;
    }
    if (OUTSCALE) { v0 *= dv; v1 *= dv; v2 *= dv; v3 *= dv; }
    if (RELU) {
      v0 = fmaxf(v0, 0.f); v1 = fmaxf(v1, 0.f);
      v2 = fmaxf(v2, 0.f); v3 = fmaxf(v3, 0.f);
    }
    if (OBF16) {
      uint2 o;
      o.x = pk2(v0, v1);
      o.y = pk2(v2, v3);
      *reinterpret_cast<uint2*>((unsigned short*)outv + (size_t)node * OS + sub * 4) = o;
    } else {
      float4 o = make_float4(v0, v1, v2, v3);
      *reinterpret_cast<float4*>((float*)outv + (size_t)node * OS + sub * 4) = o;
    }
  }
}

extern "C" void kernel_launch(void* const* d_in, const int* in_sizes, int n_in,
                              void* d_out, int out_size, void* d_ws, size_t ws_size,
                              hipStream_t stream) {
  const float* x  = (const float*)d_in[0];
  const int*   ei = (const int*)d_in[1];
  const float* W1 = (const float*)d_in[2];
  const float* b1 = (const float*)d_in[3];
  const float* W2 = (const float*)d_in[4];
  const float* b2 = (const float*)d_in[5];
  float* out = (float*)d_out;

  const int N = in_sizes[0] / 128;
  const int E = in_sizes[1] / 2;
  const int* src = ei;
  const int* dst = ei + E;

  const int nbuk = (N + 127) >> 7;
  if (nbuk > MAXBUK) return;
  const int cpb = (E + NBLK_PART - 1) / NBLK_PART;

  char* p = (char*)d_ws;
  size_t used = 0;
  auto alloc = [&](size_t bytes) -> void* {
    void* r = p + used;
    used += (bytes + 255) & ~(size_t)255;
    return r;
  };
  float* dinv    = (float*)alloc((size_t)N * 4);
  int*   row_ptr = (int*)alloc((size_t)(N + 1) * 4);
  int*   csr_src = (int*)alloc((size_t)E * 4);
  int*   buktotD = (int*)alloc((size_t)MAXBUK * 4);
  int*   buktotS = (int*)alloc((size_t)MAXBUK * 4);
  unsigned short* Wfrag1 = (unsigned short*)alloc((size_t)4 * 12 * 64 * 8 * 2);
  unsigned short* Wfrag2 = (unsigned short*)alloc((size_t)2 * 8 * 64 * 8 * 2);
  char* region = (char*)alloc((size_t)N * (64 * 4 * 2 + 64 * 2 * 2));  // 76.8 MB
  unsigned short* hb = (unsigned short*)alloc((size_t)N * 64 * 2);     // 12.8 MB
  if (used > ws_size) return;

  // layer-1 layout in region
  float* Y0f           = (float*)region;                               // [N,64] f32
  float* Y1f           = (float*)(region + (size_t)N * 64 * 4);        // [N,64] f32
  unsigned short* Ys2b = (unsigned short*)(region + (size_t)N * 64 * 8);       // [N,64] bf16
  unsigned short* Zsb  = (unsigned short*)(region + (size_t)N * 64 * 8 + (size_t)N * 64 * 2);
  // layer-2 layout aliases region (layer-1 dead by then)
  float* U0f           = (float*)region;                               // [N,40] f32
  float* U1f           = (float*)(region + (size_t)N * 40 * 4);        // [N,40] f32
  unsigned short* Us2b = (unsigned short*)(region + (size_t)N * 80 * 4);       // [N,64] bf16
  unsigned short* Z2sb = (unsigned short*)(region + (size_t)N * 80 * 4 + (size_t)N * 64 * 2);
  // radix temporaries alias region (dead before gemm1)
  unsigned int* packed = (unsigned int*)region;                        // E*4
  unsigned char* pksrc = (unsigned char*)(region + (size_t)E * 4);     // E*1
  int* histGd = (int*)(region + (size_t)E * 5 + 256);
  int* histGs = histGd + (size_t)MAXBUK * NBLK_PART;

  k_passA<<<NBLK_PART, 256, 0, stream>>>(src, dst, E, cpb, histGd, histGs, nbuk);
  k_scanA<<<2 * nbuk, 256, 0, stream>>>(histGd, histGs, buktotD, buktotS, nbuk);
  k_scanB<<<2, 256, 0, stream>>>(buktotD, buktotS, nbuk);
  k_passB<<<NBLK_PART, 256, 0, stream>>>(src, dst, E, cpb, histGd, histGs, buktotD, buktotS,
                                         nbuk, packed, pksrc);
  k_passC<<<nbuk, 256, 0, stream>>>(packed, buktotD, nbuk, E, N, csr_src, row_ptr);
  k_passC2<<<nbuk, 256, 0, stream>>>(pksrc, buktotS, nbuk, E, N, dinv);

  k_wfrag<<<(4 * 12 * 64 + 255) / 256, 256, 0, stream>>>(W1, Wfrag1, 128, 64, 12);
  k_wfrag<<<(2 * 8 * 64 + 255) / 256, 256, 0, stream>>>(W2, Wfrag2, 64, 40, 8);

  const int pb = ((size_t)N * 64 + 255) / 256;
  const int gb = (N + 63) / 64;

  // layer 1: [Y0|Y1|Ys2b] = bf16(x) @ Weff1 (Ys2 cols dinv-scaled, bf16)
  k_gemm_mfma<128, 12, false, 128, 64, 128, 192, 64, 64, 64>
      <<<gb, 256, 0, stream>>>(x, Wfrag1, dinv, Y0f, Y1f, Ys2b, N);
  // Zs = dinv*(Y1 - dinv*G(Ys2))  -> bf16
  k_prop6<64, 64, 64, false, false, true, true><<<pb, 256, 0, stream>>>(
      Ys2b, Y1f, nullptr, dinv, csr_src, row_ptr, Zsb, N);
  // h = relu(Y0 - dinv*G(Zs) + b1) -> bf16
  k_prop6<64, 64, 64, true, true, false, true><<<pb, 256, 0, stream>>>(
      Zsb, Y0f, b1, dinv, csr_src, row_ptr, hb, N);
  // layer 2: [U0|U1|Us2b] = h @ Weff2 (Us2 cols dinv-scaled, bf16)
  k_gemm_mfma<64, 8, true, 64, 40, 80, 120, 40, 40, 64>
      <<<gb, 256, 0, stream>>>(hb, Wfrag2, dinv, U0f, U1f, Us2b, N);
  // Z2s = dinv*(U1 - dinv*G(Us2)) -> bf16
  k_prop6<40, 40, 64, false, false, true, true><<<pb, 256, 0, stream>>>(
      Us2b, U1f, nullptr, dinv, csr_src, row_ptr, Z2sb, N);
  // out = U0 - dinv*G(Z2s) + b2  (fp32)
  k_prop6<40, 40, 40, false, true, false, false><<<pb, 256, 0, stream>>>(
      Z2sb, U0f, b2, dinv, csr_src, row_ptr, out, N);
}